// Round 1
// 553.345 us; speedup vs baseline: 1.0553x; 1.0553x over previous
//
#include <hip/hip_runtime.h>
#include <stdint.h>

// ============================================================================
// Attention_16441134809293 : B=1 T=2048 D=4096 N=32 KV=8 H=128, fp32 in/out.
// Round 4:
//  - k_gemm_qkv rebuilt as 256x256/8-wave counted-vmcnt pipelined GEMM
//    (T2 swizzle + T3 phase-split + T4 counted vmcnt + T5 setprio), BK=64
//    staged as two 256x32 K-slabs per tile, 2-tile LDS ring (128 KB),
//    vmcnt(6) steady state (never 0 in main loop), fused RMSNorm+RoPE
//    epilogue for 2 heads x 256 rows per block.
//  - everything else unchanged from round 3.
// Workspace map (peak 88 MB):
//   phase1 (gemm1): xb[0,16M) Wt[16,64M) Q[64,80M) K[80,84M) Vt[84,88M)
//   phase2 (attn) : att[0,16M) Ot[16,48M)  (over dead xb/Wt)
//   phase3 (gemm2): partial[48,80M)        (over dead Wt-tail/Q)
// ============================================================================

typedef __bf16 bf16x8 __attribute__((ext_vector_type(8)));
typedef float  f32x4  __attribute__((ext_vector_type(4)));

__device__ __forceinline__ uint16_t f2bf(float f) {
    union { float f; uint32_t u; } v; v.f = f;
    uint32_t r = v.u + 0x7fffu + ((v.u >> 16) & 1u);   // RNE
    return (uint16_t)(r >> 16);
}

__device__ __forceinline__ void gload_lds16(const void* g, void* l) {
    __builtin_amdgcn_global_load_lds(
        (const __attribute__((address_space(1))) uint32_t*)g,
        (__attribute__((address_space(3))) uint32_t*)l, 16, 0, 0);
}

// ------------------------------------------- x -> bf16, swizzled chunk layout
__global__ __launch_bounds__(256) void k_cvt_x(const float* __restrict__ x,
                                               uint16_t* __restrict__ xb) {
    int i = (blockIdx.x * 256 + threadIdx.x) * 8;
    int r = i >> 12, k = i & 4095;
    float4 a = *(const float4*)(x + i);
    float4 b = *(const float4*)(x + i + 4);
    uint16_t tmp[8];
    tmp[0] = f2bf(a.x); tmp[1] = f2bf(a.y); tmp[2] = f2bf(a.z); tmp[3] = f2bf(a.w);
    tmp[4] = f2bf(b.x); tmp[5] = f2bf(b.y); tmp[6] = f2bf(b.z); tmp[7] = f2bf(b.w);
    int dst = r * 4096 + (k & ~63) + (((((k >> 3) & 7) ^ (r & 7))) << 3);
    *(uint4*)(xb + dst) = *(uint4*)tmp;
}

// ---------------- q_w/kv_w -> Wt[c][d] bf16 (B^T layout, c=head*128+h), swizzled
__global__ __launch_bounds__(256) void k_prep_wt(const float* __restrict__ qw,
                                                 const float* __restrict__ kvw,
                                                 uint16_t* __restrict__ Wt) {
    const int hx = blockIdx.x, dx = blockIdx.y, m = blockIdx.z;
    const float* src = (m < 32) ? (qw + (size_t)m * 524288)
                                : (kvw + (size_t)(m - 32) * 524288);
    __shared__ uint16_t tile[64][65];                            // [d][h]
    const int t = threadIdx.x, d0 = dx * 64, h0 = hx * 64;
#pragma unroll
    for (int i = 0; i < 16; ++i) {
        int idx = i * 256 + t, r = idx >> 6, c = idx & 63;
        tile[r][c] = f2bf(src[(size_t)(d0 + r) * 128 + h0 + c]);
    }
    __syncthreads();
#pragma unroll
    for (int it = 0; it < 2; ++it) {
        int slot = it * 256 + t, hr = slot >> 3, cl = slot & 7;
        int R = m * 128 + h0 + hr;
        uint16_t tmp[8];
#pragma unroll
        for (int e = 0; e < 8; ++e) tmp[e] = tile[cl * 8 + e][hr];
        *(uint4*)&Wt[(size_t)R * 4096 + d0 + ((cl ^ (R & 7)) << 3)] = *(uint4*)tmp;
    }
}

// --------------------- o_w[n][h][d] -> Ot[d][n*128+h] bf16 (B^T), swizzled
__global__ __launch_bounds__(256) void k_prep_ot(const float* __restrict__ ow,
                                                 uint16_t* __restrict__ Ot) {
    const int dx = blockIdx.x, hx = blockIdx.y, n = blockIdx.z;
    const float* src = ow + (size_t)n * 524288;                  // [128][4096]
    __shared__ uint16_t tile[64][65];                            // [h][d]
    const int t = threadIdx.x, h0 = hx * 64, d0 = dx * 64;
#pragma unroll
    for (int i = 0; i < 16; ++i) {
        int idx = i * 256 + t, r = idx >> 6, c = idx & 63;
        tile[r][c] = f2bf(src[(size_t)(h0 + r) * 4096 + d0 + c]);
    }
    __syncthreads();
#pragma unroll
    for (int it = 0; it < 2; ++it) {
        int slot = it * 256 + t, dr = slot >> 3, cl = slot & 7;
        int R = d0 + dr;
        uint16_t tmp[8];
#pragma unroll
        for (int e = 0; e < 8; ++e) tmp[e] = tile[cl * 8 + e][dr];
        *(uint4*)&Ot[(size_t)R * 4096 + n * 128 + h0 + ((cl ^ (R & 7)) << 3)] = *(uint4*)tmp;
    }
}

// ============================================================================
// gemm1 + fused RMSNorm/RoPE epilogue, 256x256 tile, 8 waves, pipelined.
// LDS (dynamic 137216 B):
//   K-loop:  A-slabs lds[0,32768) elems  : 4 slabs of [256 rows][32 k]
//            B-slabs lds[32768,65536)    : 4 slabs of [256 rows][32 k]
//            slab = (tile&1)*2 + khalf; chunk swizzle: c ^= (row>>1)&3
//   epilogue: X fp32 [128][260] at [0,133120) ; ssq [256][4] at [133120,137216)
// Pipeline per tile (4 phases): p0 {ldA(kc0)+ldB(kc0,ch0), stage A-Kh1(T+1)},
//   p1 {ldB(kc0,ch1), vmcnt(6), stage B-Kh1(T+1)}, p2 {ldA(kc1)+ldB(kc1,ch0),
//   stage A-Kh0(T+2)}, p3 {ldB(kc1,ch1), vmcnt(6), stage B-Kh0(T+2)}.
// Each phase: ... -> barrier -> lgkmcnt(0) -> setprio(1) 16xMFMA setprio(0)
//   -> barrier. vmcnt never drains to 0 in the main loop.
// ============================================================================

#define PH_BAR do { asm volatile("" ::: "memory"); \
                    __builtin_amdgcn_s_barrier(); \
                    asm volatile("" ::: "memory"); } while (0)
#define WAIT_LGKM do { asm volatile("s_waitcnt lgkmcnt(0)" ::: "memory"); \
                       __builtin_amdgcn_sched_barrier(0); } while (0)
#define WAIT_VM(N) do { asm volatile("s_waitcnt vmcnt(" #N ")" ::: "memory"); \
                        __builtin_amdgcn_sched_barrier(0); } while (0)

__global__ __launch_bounds__(512, 2) void k_gemm_qkv(const uint16_t* __restrict__ A,
                                                     const uint16_t* __restrict__ Bt,
                                                     const int* __restrict__ pos,
                                                     const float* __restrict__ qs,
                                                     const float* __restrict__ ks,
                                                     uint16_t* __restrict__ Qg,
                                                     uint16_t* __restrict__ Kg,
                                                     uint16_t* __restrict__ Vg) {
    extern __shared__ __align__(16) char smem[];
    uint16_t* lds = (uint16_t*)smem;
    const int Kd = 4096;
    const int t = threadIdx.x, wid = t >> 6, lane = t & 63;
    const int l16 = lane & 15, quad = lane >> 4;
    const int wr = wid >> 2, wc = wid & 3;
    const int bx = blockIdx.x, bm0 = blockIdx.y * 256, bn0 = bx * 256;

    f32x4 acc[8][4];
    const f32x4 z4 = {0.f, 0.f, 0.f, 0.f};
#pragma unroll
    for (int i = 0; i < 8; ++i)
#pragma unroll
        for (int j = 0; j < 4; ++j) acc[i][j] = z4;

    // ---- staging addresses (global pre-swizzled; LDS written linearly) ----
    const int r0 = wid * 16 + (lane >> 2), c4 = lane & 3;
    const int sw2 = (r0 >> 1) & 3, sw7 = r0 & 7;
    const int offK0 = (((c4 ^ sw2)) ^ sw7) * 8;        // khalf 0: logical chunk L=c^sw2
    const int offK1 = ((4 + (c4 ^ sw2)) ^ sw7) * 8;    // khalf 1: L=4+(c^sw2)
    const uint16_t* pA0 = A + (size_t)(bm0 + r0) * Kd;
    const uint16_t* pA1 = pA0 + (size_t)128 * Kd;
    const uint16_t* pB0 = Bt + (size_t)(bn0 + r0) * Kd;
    const uint16_t* pB1 = pB0 + (size_t)128 * Kd;
    uint16_t* stA = lds + wid * 512;
    uint16_t* stB = lds + 32768 + wid * 512;

    // ---- ds-read fragment bases ----
    const int sA = (l16 >> 1) & 3;
    const int rdA = (wr * 128 + l16) * 32 + ((quad ^ sA) << 3);
    const int rdB = 32768 + (wc * 64 + l16) * 32 + ((quad ^ sA) << 3);

    bf16x8 af[8], bf0, bf1;

#define STAGE_A(SLAB, OFF, TT) do { \
    gload_lds16(pA0 + (size_t)(TT) * 64 + (OFF), stA + (SLAB) * 8192); \
    gload_lds16(pA1 + (size_t)(TT) * 64 + (OFF), stA + (SLAB) * 8192 + 4096); } while (0)
#define STAGE_B(SLAB, OFF, TT) do { \
    gload_lds16(pB0 + (size_t)(TT) * 64 + (OFF), stB + (SLAB) * 8192); \
    gload_lds16(pB1 + (size_t)(TT) * 64 + (OFF), stB + (SLAB) * 8192 + 4096); } while (0)
#define LOAD_AF(SLAB) do { _Pragma("unroll") \
    for (int i_ = 0; i_ < 8; ++i_) \
        af[i_] = *(const bf16x8*)&lds[(SLAB) * 8192 + rdA + i_ * 512]; } while (0)
#define LOAD_BF(SLAB, CH) do { \
    bf0 = *(const bf16x8*)&lds[(SLAB) * 8192 + rdB + (CH) * 1024]; \
    bf1 = *(const bf16x8*)&lds[(SLAB) * 8192 + rdB + (CH) * 1024 + 512]; } while (0)
#define MFMA_PH(CH) do { __builtin_amdgcn_s_setprio(1); \
    _Pragma("unroll") for (int i_ = 0; i_ < 8; ++i_) { \
        acc[i_][2*(CH)]   = __builtin_amdgcn_mfma_f32_16x16x32_bf16(af[i_], bf0, acc[i_][2*(CH)],   0, 0, 0); \
        acc[i_][2*(CH)+1] = __builtin_amdgcn_mfma_f32_16x16x32_bf16(af[i_], bf1, acc[i_][2*(CH)+1], 0, 0, 0); } \
    __builtin_amdgcn_s_setprio(0); } while (0)

#define TILE(TT, BUF) do { \
    /* p0: kc=0 ch=0 */ \
    LOAD_AF(2*(BUF)); LOAD_BF(2*(BUF), 0); \
    STAGE_A((((BUF)^1)*2+1), offK1, (TT)+1); \
    PH_BAR; WAIT_LGKM; MFMA_PH(0); PH_BAR; \
    /* p1: kc=0 ch=1 */ \
    LOAD_BF(2*(BUF), 1); \
    WAIT_VM(6); \
    STAGE_B((((BUF)^1)*2+1), offK1, (TT)+1); \
    PH_BAR; WAIT_LGKM; MFMA_PH(1); PH_BAR; \
    /* p2: kc=1 ch=0 */ \
    LOAD_AF(2*(BUF)+1); LOAD_BF(2*(BUF)+1, 0); \
    STAGE_A((BUF)*2, offK0, (TT)+2); \
    PH_BAR; WAIT_LGKM; MFMA_PH(0); PH_BAR; \
    /* p3: kc=1 ch=1 */ \
    LOAD_BF(2*(BUF)+1, 1); \
    WAIT_VM(6); \
    STAGE_B((BUF)*2, offK0, (TT)+2); \
    PH_BAR; WAIT_LGKM; MFMA_PH(1); PH_BAR; \
} while (0)

    // ---- prologue: tiles 0 (both K-halves) + tile 1 (K-half 0); 12 loads ----
    STAGE_A(0, offK0, 0); STAGE_B(0, offK0, 0);
    STAGE_A(1, offK1, 0); STAGE_B(1, offK1, 0);
    STAGE_A(2, offK0, 1); STAGE_B(2, offK0, 1);
    WAIT_VM(8);                 // lands A-Kh0(0), B-Kh0(0)
    PH_BAR;

    // ---- main loop: tiles 0..61 (stages reference tiles up to 63) ----
#pragma unroll 1
    for (int Ti = 0; Ti < 31; ++Ti) {
        TILE(2 * Ti, 0);
        TILE(2 * Ti + 1, 1);
    }

    // ---- tail: stage last K-half of tile 63, drain once, compute 62..63 ----
    STAGE_A(3, offK1, 63); STAGE_B(3, offK1, 63);
    WAIT_VM(0);
    PH_BAR;
#pragma unroll
    for (int T = 62; T < 64; ++T) {
        const int BUF = T & 1;
        LOAD_AF(2*BUF);   LOAD_BF(2*BUF, 0);   PH_BAR; WAIT_LGKM; MFMA_PH(0); PH_BAR;
        LOAD_BF(2*BUF, 1);                     PH_BAR; WAIT_LGKM; MFMA_PH(1); PH_BAR;
        LOAD_AF(2*BUF+1); LOAD_BF(2*BUF+1, 0); PH_BAR; WAIT_LGKM; MFMA_PH(0); PH_BAR;
        LOAD_BF(2*BUF+1, 1);                   PH_BAR; WAIT_LGKM; MFMA_PH(1); PH_BAR;
    }

#undef TILE
#undef MFMA_PH
#undef LOAD_BF
#undef LOAD_AF
#undef STAGE_B
#undef STAGE_A

    // ---------------- fused epilogue: RMSNorm + RoPE + store ----------------
    float* X   = (float*)smem;                 // [128][260] fp32 (row pad: no conflicts)
    float* ssq = (float*)(smem + 133120);      // [256 rows][2 heads][2 partials]

#pragma unroll
    for (int i = 0; i < 8; ++i)
#pragma unroll
        for (int r = 0; r < 4; ++r) {
            float s = 0.f;
#pragma unroll
            for (int j = 0; j < 4; ++j) s += acc[i][j][r] * acc[i][j][r];
            s += __shfl_xor(s, 1); s += __shfl_xor(s, 2);
            s += __shfl_xor(s, 4); s += __shfl_xor(s, 8);
            if (l16 == 0)
                ssq[(wr * 128 + i * 16 + quad * 4 + r) * 4 + (wc >> 1) * 2 + (wc & 1)] = s;
        }
    __syncthreads();

    const int cat = (bx < 16) ? 0 : (bx < 20 ? 1 : 2);   // 0=Q 1=K 2=V (head pairs never straddle)
    float s1 = 0.f, s2 = 0.f, invts = 0.f;
    if (cat < 2) {
        const float* sc = cat ? ks : qs;
        s1 = 1.0f + sc[lane];
        s2 = 1.0f + sc[lane + 64];
        invts = exp2f((float)lane * -0.20762050593046014f);  // 10000^(-h/64)
    }

#pragma unroll
    for (int pass = 0; pass < 2; ++pass) {
        if (wr == pass) {
#pragma unroll
            for (int i = 0; i < 8; ++i)
#pragma unroll
                for (int j = 0; j < 4; ++j)
#pragma unroll
                    for (int r = 0; r < 4; ++r)
                        X[(i * 16 + quad * 4 + r) * 260 + wc * 64 + j * 16 + l16] = acc[i][j][r];
        }
        __syncthreads();
        // RMSNorm + RoPE in place; wave handles 16 rows, lane = h in [0,64)
        for (int rr = 0; rr < 16; ++rr) {
            const int lrow = wid * 16 + rr;
            const int grow = bm0 + pass * 128 + lrow;
            float sn = 0.f, cs = 0.f;
            if (cat < 2) {
                float ang = (float)pos[grow] * invts;
                __sincosf(ang, &sn, &cs);
            }
#pragma unroll
            for (int hh = 0; hh < 2; ++hh) {
                const int sb = (pass * 128 + lrow) * 4 + hh * 2;
                float rn = rsqrtf((ssq[sb] + ssq[sb + 1]) * 0.0078125f + 1e-6f);
                float x1 = X[lrow * 260 + hh * 128 + lane];
                float x2 = X[lrow * 260 + hh * 128 + 64 + lane];
                if (cat < 2) {
                    float y1 = x1 * rn * s1, y2 = x2 * rn * s2;
                    X[lrow * 260 + hh * 128 + lane]      = y1 * cs - y2 * sn;
                    X[lrow * 260 + hh * 128 + 64 + lane] = y2 * cs + y1 * sn;
                } else {
                    X[lrow * 260 + hh * 128 + lane]      = x1 * rn;
                    X[lrow * 260 + hh * 128 + 64 + lane] = x2 * rn;
                }
            }
        }
        __syncthreads();
        // stores (bf16): 2 heads x 128 rows x 16 chunks = 4096 chunks, 8 iters
        if (cat == 2) {
            // V: transposed to Vt[(kv*128+h)][s], chunks swizzled by h&15 per 128-s block
#pragma unroll
            for (int it = 0; it < 8; ++it) {
                int slot = it * 512 + t, hh = slot >> 11, rem = slot & 2047;
                int h = rem >> 4, sc2 = rem & 15;
                uint16_t tmp[8];
#pragma unroll
                for (int e = 0; e < 8; ++e)
                    tmp[e] = f2bf(X[(sc2 * 8 + e) * 260 + hh * 128 + h]);
                int n = bx * 2 + hh;
                *(uint4*)&Vg[((size_t)(n - 40) * 128 + h) * 2048 + (bm0 + pass * 128)
                             + ((sc2 ^ (h & 15)) << 3)] = *(uint4*)tmp;
            }
        } else {
#pragma unroll
            for (int it = 0; it < 8; ++it) {
                int slot = it * 512 + t, hh = slot >> 11, rem = slot & 2047;
                int lrow = rem >> 4, c = rem & 15;
                int tg = bm0 + pass * 128 + lrow, n = bx * 2 + hh;
                f32x4 a = *(f32x4*)&X[lrow * 260 + hh * 128 + c * 8];
                f32x4 b = *(f32x4*)&X[lrow * 260 + hh * 128 + c * 8 + 4];
                uint16_t tmp[8];
#pragma unroll
                for (int e = 0; e < 4; ++e) { tmp[e] = f2bf(a[e]); tmp[4 + e] = f2bf(b[e]); }
                if (cat == 0)
                    *(uint4*)&Qg[((size_t)n * 2048 + tg) * 128 + c * 8] = *(uint4*)tmp;
                else  // K: pre-swizzled chunks by tg&15 for attn's global_load_lds
                    *(uint4*)&Kg[((size_t)(n - 32) * 2048 + tg) * 128
                                 + ((c ^ (tg & 15)) << 3)] = *(uint4*)tmp;
            }
        }
        __syncthreads();
    }
}

// --------------------- gemm2: C = att * Ot^T, split-K=2 via blockIdx.z
__global__ __launch_bounds__(256) void k_gemm2(const uint16_t* __restrict__ A,
                                               const uint16_t* __restrict__ Bt,
                                               float* __restrict__ C0,
                                               float* __restrict__ C1p,
                                               int M, int N, int Kd) {
    __shared__ uint16_t As[128 * 64];
    __shared__ uint16_t Bs[128 * 64];
    const int t = threadIdx.x;
    const int wave = t >> 6, lane = t & 63, l16 = lane & 15, quad = lane >> 4;
    const int wr = wave >> 1, wc = wave & 1;
    const int bm0 = blockIdx.y * 128, bn0 = blockIdx.x * 128;
    const int kz = blockIdx.z;
    const int sw = l16 & 7;
    float* C = kz ? C1p : C0;

    f32x4 acc[4][4];
    const f32x4 z4 = {0.f, 0.f, 0.f, 0.f};
#pragma unroll
    for (int i = 0; i < 4; ++i)
#pragma unroll
        for (int j = 0; j < 4; ++j) acc[i][j] = z4;

    const size_t laneOff = (size_t)(lane >> 3) * Kd + (lane & 7) * 8;
    const uint16_t* aBase = A  + (size_t)(bm0 + wave * 32) * Kd + laneOff;
    const uint16_t* bBase = Bt + (size_t)(bn0 + wave * 32) * Kd + laneOff;

    const int kbeg = kz * (Kd >> 1), kend = kbeg + (Kd >> 1);
    for (int kb = kbeg; kb < kend; kb += 64) {
        __syncthreads();
#pragma unroll
        for (int j = 0; j < 4; ++j) {
            gload_lds16(aBase + (size_t)j * 8 * Kd + kb, &As[(wave * 32 + j * 8) * 64]);
            gload_lds16(bBase + (size_t)j * 8 * Kd + kb, &Bs[(wave * 32 + j * 8) * 64]);
        }
        __syncthreads();
#pragma unroll
        for (int kc = 0; kc < 2; ++kc) {
            bf16x8 af[4], bf[4];
#pragma unroll
            for (int i = 0; i < 4; ++i)
                af[i] = *(const bf16x8*)&As[(wr * 64 + i * 16 + l16) * 64 + (((kc * 4 + quad) ^ sw) << 3)];
#pragma unroll
            for (int j = 0; j < 4; ++j)
                bf[j] = *(const bf16x8*)&Bs[(wc * 64 + j * 16 + l16) * 64 + (((kc * 4 + quad) ^ sw) << 3)];
#pragma unroll
            for (int i = 0; i < 4; ++i)
#pragma unroll
                for (int j = 0; j < 4; ++j)
                    acc[i][j] = __builtin_amdgcn_mfma_f32_16x16x32_bf16(af[i], bf[j], acc[i][j], 0, 0, 0);
        }
    }
#pragma unroll
    for (int i = 0; i < 4; ++i)
#pragma unroll
        for (int j = 0; j < 4; ++j) {
            int row = bm0 + wr * 64 + i * 16 + quad * 4;
            int col = bn0 + wc * 64 + j * 16 + l16;
            float* cp = C + (size_t)row * N + col;
            cp[0]             = acc[i][j][0];
            cp[(size_t)N]     = acc[i][j][1];
            cp[2 * (size_t)N] = acc[i][j][2];
            cp[3 * (size_t)N] = acc[i][j][3];
        }
}

__global__ __launch_bounds__(256) void k_reduce(float* __restrict__ out,
                                                const float* __restrict__ p) {
    int i = (blockIdx.x * 256 + threadIdx.x) * 4;
    float4 a = *(float4*)(out + i);
    float4 b = *(const float4*)(p + i);
    a.x += b.x; a.y += b.y; a.z += b.z; a.w += b.w;
    *(float4*)(out + i) = a;
}

// ----------------- Flash attention, causal, GQA. Balanced (p, 31-p) pairing.
// K/Vt staged via global_load_lds (identity copy of pre-swizzled global).
__global__ __launch_bounds__(256) void k_attn(const uint16_t* __restrict__ Q,
                                              const uint16_t* __restrict__ K,
                                              const uint16_t* __restrict__ Vt,
                                              uint16_t* __restrict__ att) {
    __shared__ uint16_t sK[128 * 128];
    __shared__ uint16_t sV[128 * 128];
    const int p = blockIdx.x, n = blockIdx.y, kk = n >> 2;
    const int t = threadIdx.x, wave = t >> 6, lane = t & 63;
    const int l16 = lane & 15, quad = lane >> 4;
    const f32x4 z4 = {0.f, 0.f, 0.f, 0.f};

    const uint16_t* Kbase = K  + ((size_t)kk * 2048 + wave * 32 + (lane >> 4)) * 128 + (lane & 15) * 8;
    const uint16_t* Vbase = Vt + ((size_t)kk * 128  + wave * 32 + (lane >> 4)) * 2048 + (lane & 15) * 8;

    for (int half = 0; half < 2; ++half) {
        const int qt = half ? (31 - p) : p;
        const int q0 = qt * 64;
        const int nk = (qt >> 1) + 1;

        bf16x8 qf[4];
#pragma unroll
        for (int kc = 0; kc < 4; ++kc)
            qf[kc] = *(const bf16x8*)(Q + (size_t)(n * 2048 + q0 + wave * 16 + l16) * 128 + kc * 32 + quad * 8);

        f32x4 O[8];
#pragma unroll
        for (int h = 0; h < 8; ++h) O[h] = z4;
        float mrow[4], lrow[4];
#pragma unroll
        for (int r = 0; r < 4; ++r) { mrow[r] = -INFINITY; lrow[r] = 0.f; }

        for (int st = 0; st < nk; ++st) {
            const int s0 = st * 128;
            __syncthreads();
#pragma unroll
            for (int j = 0; j < 8; ++j) {
                gload_lds16(Kbase + (size_t)(s0 + j * 4) * 128, &sK[(wave * 32 + j * 4) * 128]);
                gload_lds16(Vbase + (size_t)j * 4 * 2048 + s0,  &sV[(wave * 32 + j * 4) * 128]);
            }
            __syncthreads();

            f32x4 S[8];
#pragma unroll
            for (int jn = 0; jn < 8; ++jn) S[jn] = z4;
#pragma unroll
            for (int jn = 0; jn < 8; ++jn) {
                int krow = jn * 16 + l16;
#pragma unroll
                for (int kc = 0; kc < 4; ++kc) {
                    bf16x8 b = *(const bf16x8*)&sK[krow * 128 + (((kc * 4 + quad) ^ l16) << 3)];
                    S[jn] = __builtin_amdgcn_mfma_f32_16x16x32_bf16(qf[kc], b, S[jn], 0, 0, 0);
                }
            }
            if (st == nk - 1) {
#pragma unroll
                for (int jn = 0; jn < 8; ++jn) {
                    int sc = s0 + jn * 16 + l16;
#pragma unroll
                    for (int r = 0; r < 4; ++r) {
                        int mr = q0 + wave * 16 + quad * 4 + r;
                        if (sc > mr) S[jn][r] = -INFINITY;
                    }
                }
            }
            float alpha[4];
#pragma unroll
            for (int r = 0; r < 4; ++r) {
                float mx = S[0][r];
#pragma unroll
                for (int jn = 1; jn < 8; ++jn) mx = fmaxf(mx, S[jn][r]);
                mx = fmaxf(mx, __shfl_xor(mx, 1));
                mx = fmaxf(mx, __shfl_xor(mx, 2));
                mx = fmaxf(mx, __shfl_xor(mx, 4));
                mx = fmaxf(mx, __shfl_xor(mx, 8));
                float mnew = fmaxf(mrow[r], mx);
                float a = __expf(mrow[r] - mnew);
                mrow[r] = mnew;
                float sum = 0.f;
#pragma unroll
                for (int jn = 0; jn < 8; ++jn) {
                    float e = __expf(S[jn][r] - mnew);
                    S[jn][r] = e;
                    sum += e;
                }
                sum += __shfl_xor(sum, 1);
                sum += __shfl_xor(sum, 2);
                sum += __shfl_xor(sum, 4);
                sum += __shfl_xor(sum, 8);
                lrow[r] = lrow[r] * a + sum;
                alpha[r] = a;
            }
#pragma unroll
            for (int h = 0; h < 8; ++h)
#pragma unroll
                for (int r = 0; r < 4; ++r) O[h][r] *= alpha[r];

            __syncthreads();
#pragma unroll
            for (int jn = 0; jn < 8; ++jn)
#pragma unroll
                for (int r = 0; r < 4; ++r) {
                    int prow = wave * 16 + quad * 4 + r;
                    int pcol = jn * 16 + l16;
                    sK[prow * 128 + ((pcol & 7) | ((((pcol >> 3) ^ prow) & 15) << 3))]
                        = f2bf(S[jn][r]);
                }
            bf16x8 pf[4];
#pragma unroll
            for (int ksv = 0; ksv < 4; ++ksv)
                pf[ksv] = *(const bf16x8*)&sK[(wave * 16 + l16) * 128 + (((ksv * 4 + quad) ^ l16) << 3)];
#pragma unroll
            for (int hj = 0; hj < 8; ++hj) {
                int vrow = hj * 16 + l16;
#pragma unroll
                for (int ksv = 0; ksv < 4; ++ksv) {
                    bf16x8 b = *(const bf16x8*)&sV[vrow * 128 + (((ksv * 4 + quad) ^ l16) << 3)];
                    O[hj] = __builtin_amdgcn_mfma_f32_16x16x32_bf16(pf[ksv], b, O[hj], 0, 0, 0);
                }
            }
        }

        // epilogue: normalize, LDS round-trip (own-wave region), swizzled 16B stores
        __syncthreads();
        uint16_t* sO = &sK[wave * 2112];
        float inv[4];
#pragma unroll
        for (int r = 0; r < 4; ++r) inv[r] = 1.0f / lrow[r];
#pragma unroll
        for (int hj = 0; hj < 8; ++hj)
#pragma unroll
            for (int r = 0; r < 4; ++r)
                sO[(quad * 4 + r) * 132 + hj * 16 + l16] = f2bf(O[hj][r] * inv[r]);
#pragma unroll
        for (int it = 0; it < 4; ++it) {
            int slot = it * 64 + lane, rloc = slot >> 4, cl = slot & 15;
            bf16x8 v = *(const bf16x8*)&sO[rloc * 132 + cl * 8];
            int R = q0 + wave * 16 + rloc;
            size_t dst = (size_t)R * 4096 + n * 128 + ((cl & 8) << 3) + (((cl & 7) ^ (R & 7)) << 3);
            *(uint4*)&att[dst] = *(uint4*)&v;
        }
    }
}

// ============================================================================
extern "C" void kernel_launch(void* const* d_in, const int* in_sizes, int n_in,
                              void* d_out, int out_size, void* d_ws, size_t ws_size,
                              hipStream_t stream) {
    const float* x   = (const float*)d_in[0];
    const int*   sp  = (const int*)d_in[1];
    const float* qw  = (const float*)d_in[3];
    const float* kvw = (const float*)d_in[4];
    const float* ow  = (const float*)d_in[5];
    const float* qsc = (const float*)d_in[6];
    const float* ksc = (const float*)d_in[7];
    float* out = (float*)d_out;

    char* ws = (char*)d_ws;
    uint16_t* xb   = (uint16_t*)(ws);
    uint16_t* Wt   = (uint16_t*)(ws + (size_t)(16u << 20));
    uint16_t* Qb   = (uint16_t*)(ws + (size_t)(64u << 20));
    uint16_t* Kb   = (uint16_t*)(ws + (size_t)(80u << 20));
    uint16_t* Vtb  = (uint16_t*)(ws + (size_t)(84u << 20));
    uint16_t* att  = (uint16_t*)(ws);                           // over dead xb
    uint16_t* Ot   = (uint16_t*)(ws + (size_t)(16u << 20));     // over dead Wt
    float*    part = (float*)   (ws + (size_t)(48u << 20));     // over dead Wt/Q

    static bool attr_done = false;
    if (!attr_done) {
        hipFuncSetAttribute(reinterpret_cast<const void*>(k_gemm_qkv),
                            hipFuncAttributeMaxDynamicSharedMemorySize, 137216);
        attr_done = true;
    }

    k_cvt_x    <<<4096, 256, 0, stream>>>(x, xb);
    k_prep_wt  <<<dim3(2, 64, 48), 256, 0, stream>>>(qw, kvw, Wt);
    k_gemm_qkv <<<dim3(24, 8), 512, 137216, stream>>>(xb, Wt, sp, qsc, ksc, Qb, Kb, Vtb);
    k_prep_ot  <<<dim3(64, 2, 32), 256, 0, stream>>>(ow, Ot);
    k_attn     <<<dim3(16, 32), 256, 0, stream>>>(Qb, Kb, Vtb, att);
    k_gemm2    <<<dim3(32, 16, 2), 256, 0, stream>>>(att, Ot, out, part, 2048, 4096, 4096);
    k_reduce   <<<8192, 256, 0, stream>>>(out, part);
}

// Round 2
// 530.638 us; speedup vs baseline: 1.1004x; 1.0428x over previous
//
#include <hip/hip_runtime.h>
#include <stdint.h>

// ============================================================================
// Attention_16441134809293 : B=1 T=2048 D=4096 N=32 KV=8 H=128, fp32 in/out.
// Round 5:
//  - k_gemm_qkv: phases rebalanced to 8/4/8/4 ds_reads (phase = kc x i-half),
//    same vmcnt(6) pipeline. Cuts the 640-cycle LDS read bursts that stalled
//    the MFMA pipe (MfmaUtil 31%, 44% no-issue cycles).
//  - k_gemm2 -> k_gemm2p: pipelined 256x128 tile, 256 blocks (full CU
//    coverage), 6-slab LDS ring (144 KB, 3 K-tiles deep), vmcnt(6) every
//    phase, no split-K. k_reduce removed.
// Workspace map (peak 88 MB):
//   phase1 (gemm1): xb[0,16M) Wt[16,64M) Q[64,80M) K[80,84M) Vt[84,88M)
//   phase2 (attn) : att[0,16M) Ot[16,48M)  (over dead xb/Wt)
// ============================================================================

typedef __bf16 bf16x8 __attribute__((ext_vector_type(8)));
typedef float  f32x4  __attribute__((ext_vector_type(4)));

__device__ __forceinline__ uint16_t f2bf(float f) {
    union { float f; uint32_t u; } v; v.f = f;
    uint32_t r = v.u + 0x7fffu + ((v.u >> 16) & 1u);   // RNE
    return (uint16_t)(r >> 16);
}

__device__ __forceinline__ void gload_lds16(const void* g, void* l) {
    __builtin_amdgcn_global_load_lds(
        (const __attribute__((address_space(1))) uint32_t*)g,
        (__attribute__((address_space(3))) uint32_t*)l, 16, 0, 0);
}

// ------------------------------------------- x -> bf16, swizzled chunk layout
__global__ __launch_bounds__(256) void k_cvt_x(const float* __restrict__ x,
                                               uint16_t* __restrict__ xb) {
    int i = (blockIdx.x * 256 + threadIdx.x) * 8;
    int r = i >> 12, k = i & 4095;
    float4 a = *(const float4*)(x + i);
    float4 b = *(const float4*)(x + i + 4);
    uint16_t tmp[8];
    tmp[0] = f2bf(a.x); tmp[1] = f2bf(a.y); tmp[2] = f2bf(a.z); tmp[3] = f2bf(a.w);
    tmp[4] = f2bf(b.x); tmp[5] = f2bf(b.y); tmp[6] = f2bf(b.z); tmp[7] = f2bf(b.w);
    int dst = r * 4096 + (k & ~63) + (((((k >> 3) & 7) ^ (r & 7))) << 3);
    *(uint4*)(xb + dst) = *(uint4*)tmp;
}

// ---------------- q_w/kv_w -> Wt[c][d] bf16 (B^T layout, c=head*128+h), swizzled
__global__ __launch_bounds__(256) void k_prep_wt(const float* __restrict__ qw,
                                                 const float* __restrict__ kvw,
                                                 uint16_t* __restrict__ Wt) {
    const int hx = blockIdx.x, dx = blockIdx.y, m = blockIdx.z;
    const float* src = (m < 32) ? (qw + (size_t)m * 524288)
                                : (kvw + (size_t)(m - 32) * 524288);
    __shared__ uint16_t tile[64][65];                            // [d][h]
    const int t = threadIdx.x, d0 = dx * 64, h0 = hx * 64;
#pragma unroll
    for (int i = 0; i < 16; ++i) {
        int idx = i * 256 + t, r = idx >> 6, c = idx & 63;
        tile[r][c] = f2bf(src[(size_t)(d0 + r) * 128 + h0 + c]);
    }
    __syncthreads();
#pragma unroll
    for (int it = 0; it < 2; ++it) {
        int slot = it * 256 + t, hr = slot >> 3, cl = slot & 7;
        int R = m * 128 + h0 + hr;
        uint16_t tmp[8];
#pragma unroll
        for (int e = 0; e < 8; ++e) tmp[e] = tile[cl * 8 + e][hr];
        *(uint4*)&Wt[(size_t)R * 4096 + d0 + ((cl ^ (R & 7)) << 3)] = *(uint4*)tmp;
    }
}

// --------------------- o_w[n][h][d] -> Ot[d][n*128+h] bf16 (B^T), swizzled
__global__ __launch_bounds__(256) void k_prep_ot(const float* __restrict__ ow,
                                                 uint16_t* __restrict__ Ot) {
    const int dx = blockIdx.x, hx = blockIdx.y, n = blockIdx.z;
    const float* src = ow + (size_t)n * 524288;                  // [128][4096]
    __shared__ uint16_t tile[64][65];                            // [h][d]
    const int t = threadIdx.x, h0 = hx * 64, d0 = dx * 64;
#pragma unroll
    for (int i = 0; i < 16; ++i) {
        int idx = i * 256 + t, r = idx >> 6, c = idx & 63;
        tile[r][c] = f2bf(src[(size_t)(h0 + r) * 4096 + d0 + c]);
    }
    __syncthreads();
#pragma unroll
    for (int it = 0; it < 2; ++it) {
        int slot = it * 256 + t, dr = slot >> 3, cl = slot & 7;
        int R = d0 + dr;
        uint16_t tmp[8];
#pragma unroll
        for (int e = 0; e < 8; ++e) tmp[e] = tile[cl * 8 + e][dr];
        *(uint4*)&Ot[(size_t)R * 4096 + n * 128 + h0 + ((cl ^ (R & 7)) << 3)] = *(uint4*)tmp;
    }
}

// ---------------------------------------------------------------- sync macros
#define PH_BAR do { asm volatile("" ::: "memory"); \
                    __builtin_amdgcn_s_barrier(); \
                    asm volatile("" ::: "memory"); } while (0)
#define WAIT_LGKM do { asm volatile("s_waitcnt lgkmcnt(0)" ::: "memory"); \
                       __builtin_amdgcn_sched_barrier(0); } while (0)
#define WAIT_VM(N) do { asm volatile("s_waitcnt vmcnt(" #N ")" ::: "memory"); \
                        __builtin_amdgcn_sched_barrier(0); } while (0)

// ============================================================================
// gemm1 + fused RMSNorm/RoPE epilogue, 256x256 tile, 8 waves, pipelined.
// LDS (dynamic 137216 B):
//   K-loop:  A-slabs lds[0,32768) elems  : 4 slabs of [256 rows][32 k]
//            B-slabs lds[32768,65536)    : 4 slabs of [256 rows][32 k]
//            slab = (tile&1)*2 + khalf; chunk swizzle: c ^= (row>>1)&3
//   epilogue: X fp32 [128][260] at [0,133120) ; ssq [256][4] at [133120,137216)
// Phase = (khalf, i-half): reads 8/4/8/4 b128 per wave (balanced), 16 MFMA
// each. vmcnt(6) at p1/p3 only.
// ============================================================================
__global__ __launch_bounds__(512, 2) void k_gemm_qkv(const uint16_t* __restrict__ A,
                                                     const uint16_t* __restrict__ Bt,
                                                     const int* __restrict__ pos,
                                                     const float* __restrict__ qs,
                                                     const float* __restrict__ ks,
                                                     uint16_t* __restrict__ Qg,
                                                     uint16_t* __restrict__ Kg,
                                                     uint16_t* __restrict__ Vg) {
    extern __shared__ __align__(16) char smem[];
    uint16_t* lds = (uint16_t*)smem;
    const int Kd = 4096;
    const int t = threadIdx.x, wid = t >> 6, lane = t & 63;
    const int l16 = lane & 15, quad = lane >> 4;
    const int wr = wid >> 2, wc = wid & 3;
    const int bx = blockIdx.x, bm0 = blockIdx.y * 256, bn0 = bx * 256;

    f32x4 acc[8][4];
    const f32x4 z4 = {0.f, 0.f, 0.f, 0.f};
#pragma unroll
    for (int i = 0; i < 8; ++i)
#pragma unroll
        for (int j = 0; j < 4; ++j) acc[i][j] = z4;

    // ---- staging addresses (global pre-swizzled; LDS written linearly) ----
    const int r0 = wid * 16 + (lane >> 2), c4 = lane & 3;
    const int sw2 = (r0 >> 1) & 3, sw7 = r0 & 7;
    const int offK0 = (((c4 ^ sw2)) ^ sw7) * 8;        // khalf 0: logical chunk L=c^sw2
    const int offK1 = ((4 + (c4 ^ sw2)) ^ sw7) * 8;    // khalf 1: L=4+(c^sw2)
    const uint16_t* pA0 = A + (size_t)(bm0 + r0) * Kd;
    const uint16_t* pA1 = pA0 + (size_t)128 * Kd;
    const uint16_t* pB0 = Bt + (size_t)(bn0 + r0) * Kd;
    const uint16_t* pB1 = pB0 + (size_t)128 * Kd;
    uint16_t* stA = lds + wid * 512;
    uint16_t* stB = lds + 32768 + wid * 512;

    // ---- ds-read fragment bases ----
    const int sA = (l16 >> 1) & 3;
    const int rdA = (wr * 128 + l16) * 32 + ((quad ^ sA) << 3);
    const int rdB = 32768 + (wc * 64 + l16) * 32 + ((quad ^ sA) << 3);

    bf16x8 af[4], bf[4];

#define STAGE_A(SLAB, OFF, TT) do { \
    gload_lds16(pA0 + (size_t)(TT) * 64 + (OFF), stA + (SLAB) * 8192); \
    gload_lds16(pA1 + (size_t)(TT) * 64 + (OFF), stA + (SLAB) * 8192 + 4096); } while (0)
#define STAGE_B(SLAB, OFF, TT) do { \
    gload_lds16(pB0 + (size_t)(TT) * 64 + (OFF), stB + (SLAB) * 8192); \
    gload_lds16(pB1 + (size_t)(TT) * 64 + (OFF), stB + (SLAB) * 8192 + 4096); } while (0)
#define LOAD_AF4(SLAB, I0) do { _Pragma("unroll") \
    for (int i_ = 0; i_ < 4; ++i_) \
        af[i_] = *(const bf16x8*)&lds[(SLAB) * 8192 + rdA + ((I0) + i_) * 512]; } while (0)
#define LOAD_BF4(SLAB) do { _Pragma("unroll") \
    for (int j_ = 0; j_ < 4; ++j_) \
        bf[j_] = *(const bf16x8*)&lds[(SLAB) * 8192 + rdB + j_ * 512]; } while (0)
#define MFMA_PH(I0) do { __builtin_amdgcn_s_setprio(1); \
    _Pragma("unroll") for (int i_ = 0; i_ < 4; ++i_) \
        _Pragma("unroll") for (int j_ = 0; j_ < 4; ++j_) \
            acc[(I0) + i_][j_] = __builtin_amdgcn_mfma_f32_16x16x32_bf16(af[i_], bf[j_], acc[(I0) + i_][j_], 0, 0, 0); \
    __builtin_amdgcn_s_setprio(0); } while (0)

#define TILE(TT, BUF) do { \
    /* p0: kc0, i 0-3 */ \
    LOAD_BF4(2*(BUF)); LOAD_AF4(2*(BUF), 0); \
    STAGE_A((((BUF)^1)*2+1), offK1, (TT)+1); \
    PH_BAR; WAIT_LGKM; MFMA_PH(0); PH_BAR; \
    /* p1: kc0, i 4-7 */ \
    LOAD_AF4(2*(BUF), 4); \
    WAIT_VM(6); \
    STAGE_B((((BUF)^1)*2+1), offK1, (TT)+1); \
    PH_BAR; WAIT_LGKM; MFMA_PH(4); PH_BAR; \
    /* p2: kc1, i 0-3 */ \
    LOAD_BF4(2*(BUF)+1); LOAD_AF4(2*(BUF)+1, 0); \
    STAGE_A((BUF)*2, offK0, (TT)+2); \
    PH_BAR; WAIT_LGKM; MFMA_PH(0); PH_BAR; \
    /* p3: kc1, i 4-7 */ \
    LOAD_AF4(2*(BUF)+1, 4); \
    WAIT_VM(6); \
    STAGE_B((BUF)*2, offK0, (TT)+2); \
    PH_BAR; WAIT_LGKM; MFMA_PH(4); PH_BAR; \
} while (0)

    // ---- prologue: tiles 0 (both K-halves) + tile 1 (K-half 0); 12 loads ----
    STAGE_A(0, offK0, 0); STAGE_B(0, offK0, 0);
    STAGE_A(1, offK1, 0); STAGE_B(1, offK1, 0);
    STAGE_A(2, offK0, 1); STAGE_B(2, offK0, 1);
    WAIT_VM(8);                 // lands A-Kh0(0), B-Kh0(0)
    PH_BAR;

    // ---- main loop: tiles 0..61 (stages reference tiles up to 63) ----
#pragma unroll 1
    for (int Ti = 0; Ti < 31; ++Ti) {
        TILE(2 * Ti, 0);
        TILE(2 * Ti + 1, 1);
    }

    // ---- tail: stage last K-half of tile 63, drain once, compute 62..63 ----
    STAGE_A(3, offK1, 63); STAGE_B(3, offK1, 63);
    WAIT_VM(0);
    PH_BAR;
#pragma unroll
    for (int T = 62; T < 64; ++T) {
        const int BUF = T & 1;
        LOAD_BF4(2*BUF); LOAD_AF4(2*BUF, 0);     PH_BAR; WAIT_LGKM; MFMA_PH(0); PH_BAR;
        LOAD_AF4(2*BUF, 4);                      PH_BAR; WAIT_LGKM; MFMA_PH(4); PH_BAR;
        LOAD_BF4(2*BUF+1); LOAD_AF4(2*BUF+1, 0); PH_BAR; WAIT_LGKM; MFMA_PH(0); PH_BAR;
        LOAD_AF4(2*BUF+1, 4);                    PH_BAR; WAIT_LGKM; MFMA_PH(4); PH_BAR;
    }

#undef TILE
#undef MFMA_PH
#undef LOAD_BF4
#undef LOAD_AF4
#undef STAGE_B
#undef STAGE_A

    // ---------------- fused epilogue: RMSNorm + RoPE + store ----------------
    float* X   = (float*)smem;                 // [128][260] fp32 (row pad: no conflicts)
    float* ssq = (float*)(smem + 133120);      // [256 rows][2 heads][2 partials]

#pragma unroll
    for (int i = 0; i < 8; ++i)
#pragma unroll
        for (int r = 0; r < 4; ++r) {
            float s = 0.f;
#pragma unroll
            for (int j = 0; j < 4; ++j) s += acc[i][j][r] * acc[i][j][r];
            s += __shfl_xor(s, 1); s += __shfl_xor(s, 2);
            s += __shfl_xor(s, 4); s += __shfl_xor(s, 8);
            if (l16 == 0)
                ssq[(wr * 128 + i * 16 + quad * 4 + r) * 4 + (wc >> 1) * 2 + (wc & 1)] = s;
        }
    __syncthreads();

    const int cat = (bx < 16) ? 0 : (bx < 20 ? 1 : 2);   // 0=Q 1=K 2=V (head pairs never straddle)
    float s1 = 0.f, s2 = 0.f, invts = 0.f;
    if (cat < 2) {
        const float* sc = cat ? ks : qs;
        s1 = 1.0f + sc[lane];
        s2 = 1.0f + sc[lane + 64];
        invts = exp2f((float)lane * -0.20762050593046014f);  // 10000^(-h/64)
    }

#pragma unroll
    for (int pass = 0; pass < 2; ++pass) {
        if (wr == pass) {
#pragma unroll
            for (int i = 0; i < 8; ++i)
#pragma unroll
                for (int j = 0; j < 4; ++j)
#pragma unroll
                    for (int r = 0; r < 4; ++r)
                        X[(i * 16 + quad * 4 + r) * 260 + wc * 64 + j * 16 + l16] = acc[i][j][r];
        }
        __syncthreads();
        // RMSNorm + RoPE in place; wave handles 16 rows, lane = h in [0,64)
        for (int rr = 0; rr < 16; ++rr) {
            const int lrow = wid * 16 + rr;
            const int grow = bm0 + pass * 128 + lrow;
            float sn = 0.f, cs = 0.f;
            if (cat < 2) {
                float ang = (float)pos[grow] * invts;
                __sincosf(ang, &sn, &cs);
            }
#pragma unroll
            for (int hh = 0; hh < 2; ++hh) {
                const int sb = (pass * 128 + lrow) * 4 + hh * 2;
                float rn = rsqrtf((ssq[sb] + ssq[sb + 1]) * 0.0078125f + 1e-6f);
                float x1 = X[lrow * 260 + hh * 128 + lane];
                float x2 = X[lrow * 260 + hh * 128 + 64 + lane];
                if (cat < 2) {
                    float y1 = x1 * rn * s1, y2 = x2 * rn * s2;
                    X[lrow * 260 + hh * 128 + lane]      = y1 * cs - y2 * sn;
                    X[lrow * 260 + hh * 128 + 64 + lane] = y2 * cs + y1 * sn;
                } else {
                    X[lrow * 260 + hh * 128 + lane]      = x1 * rn;
                    X[lrow * 260 + hh * 128 + 64 + lane] = x2 * rn;
                }
            }
        }
        __syncthreads();
        // stores (bf16): 2 heads x 128 rows x 16 chunks = 4096 chunks, 8 iters
        if (cat == 2) {
            // V: transposed to Vt[(kv*128+h)][s], chunks swizzled by h&15 per 128-s block
#pragma unroll
            for (int it = 0; it < 8; ++it) {
                int slot = it * 512 + t, hh = slot >> 11, rem = slot & 2047;
                int h = rem >> 4, sc2 = rem & 15;
                uint16_t tmp[8];
#pragma unroll
                for (int e = 0; e < 8; ++e)
                    tmp[e] = f2bf(X[(sc2 * 8 + e) * 260 + hh * 128 + h]);
                int n = bx * 2 + hh;
                *(uint4*)&Vg[((size_t)(n - 40) * 128 + h) * 2048 + (bm0 + pass * 128)
                             + ((sc2 ^ (h & 15)) << 3)] = *(uint4*)tmp;
            }
        } else {
#pragma unroll
            for (int it = 0; it < 8; ++it) {
                int slot = it * 512 + t, hh = slot >> 11, rem = slot & 2047;
                int lrow = rem >> 4, c = rem & 15;
                int tg = bm0 + pass * 128 + lrow, n = bx * 2 + hh;
                f32x4 a = *(f32x4*)&X[lrow * 260 + hh * 128 + c * 8];
                f32x4 b = *(f32x4*)&X[lrow * 260 + hh * 128 + c * 8 + 4];
                uint16_t tmp[8];
#pragma unroll
                for (int e = 0; e < 4; ++e) { tmp[e] = f2bf(a[e]); tmp[4 + e] = f2bf(b[e]); }
                if (cat == 0)
                    *(uint4*)&Qg[((size_t)n * 2048 + tg) * 128 + c * 8] = *(uint4*)tmp;
                else  // K: pre-swizzled chunks by tg&15 for attn's global_load_lds
                    *(uint4*)&Kg[((size_t)(n - 32) * 2048 + tg) * 128
                                 + ((c ^ (tg & 15)) << 3)] = *(uint4*)tmp;
            }
        }
        __syncthreads();
    }
}

// ============================================================================
// gemm2: out = att(2048x4096) * Ot^T(4096x4096), pipelined 256x128 tile.
// 256 blocks (full CU coverage), 8 waves (4x2), per-wave 64x64, acc[4][4].
// LDS 147456 B: A 6 slabs x [256][32k] (16 KB) + B 6 slabs x [128][32k] (8 KB)
//   = 3-K-tile ring. Each phase: 8 ds_reads, vmcnt(6) (retires the group
//   needed next phase; staged 3 phases earlier), stage 3 gloads, barrier,
//   lgkm(0), 16 MFMA, barrier.
// ============================================================================
__global__ __launch_bounds__(512, 2) void k_gemm2p(const uint16_t* __restrict__ A,
                                                   const uint16_t* __restrict__ Bt,
                                                   float* __restrict__ C) {
    extern __shared__ __align__(16) char smem2[];
    uint16_t* lds = (uint16_t*)smem2;
    const int Kd = 4096, Nn = 4096;
    const int t = threadIdx.x, wid = t >> 6, lane = t & 63;
    const int l16 = lane & 15, quad = lane >> 4;
    const int wr = wid >> 1, wc = wid & 1;
    const int bm0 = blockIdx.y * 256, bn0 = blockIdx.x * 128;

    f32x4 acc[4][4];
    const f32x4 z4 = {0.f, 0.f, 0.f, 0.f};
#pragma unroll
    for (int i = 0; i < 4; ++i)
#pragma unroll
        for (int j = 0; j < 4; ++j) acc[i][j] = z4;

    const int r0 = wid * 16 + (lane >> 2), c4 = lane & 3;
    const int sw2 = (r0 >> 1) & 3, sw7 = r0 & 7;
    const int offK0 = ((c4 ^ sw2) ^ sw7) * 8;
    const int offK1 = ((4 + (c4 ^ sw2)) ^ sw7) * 8;
    const uint16_t* pA0 = A + (size_t)(bm0 + r0) * Kd;
    const uint16_t* pA1 = pA0 + (size_t)128 * Kd;
    const uint16_t* pB0 = Bt + (size_t)(bn0 + r0) * Kd;
    uint16_t* stA = lds + wid * 512;
    uint16_t* stB = lds + 49152 + wid * 512;

    const int sA = (l16 >> 1) & 3;
    const int rdA = (wr * 64 + l16) * 32 + ((quad ^ sA) << 3);
    const int rdB = 49152 + (wc * 64 + l16) * 32 + ((quad ^ sA) << 3);

    bf16x8 af[4], bf[4];

#define G2_STAGE(SLAB, OFF, TT) do { \
    gload_lds16(pA0 + (size_t)(TT) * 64 + (OFF), stA + (SLAB) * 8192); \
    gload_lds16(pA1 + (size_t)(TT) * 64 + (OFF), stA + (SLAB) * 8192 + 4096); \
    gload_lds16(pB0 + (size_t)(TT) * 64 + (OFF), stB + (SLAB) * 4096); } while (0)

#define G2_MFMA do { __builtin_amdgcn_s_setprio(1); \
    _Pragma("unroll") for (int i_ = 0; i_ < 4; ++i_) \
        _Pragma("unroll") for (int j_ = 0; j_ < 4; ++j_) \
            acc[i_][j_] = __builtin_amdgcn_mfma_f32_16x16x32_bf16(af[i_], bf[j_], acc[i_][j_], 0, 0, 0); \
    __builtin_amdgcn_s_setprio(0); } while (0)

#define G2_LOAD(CS) do { _Pragma("unroll") \
    for (int i_ = 0; i_ < 4; ++i_) \
        af[i_] = *(const bf16x8*)&lds[(CS) * 8192 + rdA + i_ * 512]; \
    _Pragma("unroll") for (int j_ = 0; j_ < 4; ++j_) \
        bf[j_] = *(const bf16x8*)&lds[(CS) * 4096 + rdB + j_ * 512]; } while (0)

#define G2_PH(CS, SG, OFF, TT) do { \
    G2_LOAD(CS); \
    WAIT_VM(6); \
    G2_STAGE((SG), (OFF), (TT)); \
    PH_BAR; WAIT_LGKM; G2_MFMA; PH_BAR; } while (0)

#define G2_PHT(CS, VMN) do { \
    G2_LOAD(CS); \
    WAIT_VM(VMN); \
    PH_BAR; WAIT_LGKM; G2_MFMA; PH_BAR; } while (0)

    // prologue: stage T0 kc0/kc1, T1 kc0/kc1 (12 loads), land T0 kc0
    G2_STAGE(0, offK0, 0);
    G2_STAGE(1, offK1, 0);
    G2_STAGE(2, offK0, 1);
    G2_STAGE(3, offK1, 1);
    WAIT_VM(9);
    PH_BAR;

    // main loop: tiles 0..59 (period-3 slab rotation); stages reach tile 61
#pragma unroll 1
    for (int Tb = 0; Tb < 60; Tb += 3) {
        G2_PH(0, 4, offK0, Tb + 2);  G2_PH(1, 5, offK1, Tb + 2);
        G2_PH(2, 0, offK0, Tb + 3);  G2_PH(3, 1, offK1, Tb + 3);
        G2_PH(4, 2, offK0, Tb + 4);  G2_PH(5, 3, offK1, Tb + 4);
    }
    // T=60, 61 (stage tiles 62, 63)
    G2_PH(0, 4, offK0, 62);  G2_PH(1, 5, offK1, 62);
    G2_PH(2, 0, offK0, 63);  G2_PH(3, 1, offK1, 63);
    // T=62, 63: drain
    G2_PHT(4, 6); G2_PHT(5, 3); G2_PHT(0, 0); G2_PHT(1, 0);

#undef G2_PHT
#undef G2_PH
#undef G2_LOAD
#undef G2_MFMA
#undef G2_STAGE

#pragma unroll
    for (int i = 0; i < 4; ++i)
#pragma unroll
        for (int j = 0; j < 4; ++j) {
            int row = bm0 + wr * 64 + i * 16 + quad * 4;
            int col = bn0 + wc * 64 + j * 16 + l16;
            float* cp = C + (size_t)row * Nn + col;
            cp[0]              = acc[i][j][0];
            cp[(size_t)Nn]     = acc[i][j][1];
            cp[2 * (size_t)Nn] = acc[i][j][2];
            cp[3 * (size_t)Nn] = acc[i][j][3];
        }
}

// ----------------- Flash attention, causal, GQA. Balanced (p, 31-p) pairing.
// K/Vt staged via global_load_lds (identity copy of pre-swizzled global).
__global__ __launch_bounds__(256) void k_attn(const uint16_t* __restrict__ Q,
                                              const uint16_t* __restrict__ K,
                                              const uint16_t* __restrict__ Vt,
                                              uint16_t* __restrict__ att) {
    __shared__ uint16_t sK[128 * 128];
    __shared__ uint16_t sV[128 * 128];
    const int p = blockIdx.x, n = blockIdx.y, kk = n >> 2;
    const int t = threadIdx.x, wave = t >> 6, lane = t & 63;
    const int l16 = lane & 15, quad = lane >> 4;
    const f32x4 z4 = {0.f, 0.f, 0.f, 0.f};

    const uint16_t* Kbase = K  + ((size_t)kk * 2048 + wave * 32 + (lane >> 4)) * 128 + (lane & 15) * 8;
    const uint16_t* Vbase = Vt + ((size_t)kk * 128  + wave * 32 + (lane >> 4)) * 2048 + (lane & 15) * 8;

    for (int half = 0; half < 2; ++half) {
        const int qt = half ? (31 - p) : p;
        const int q0 = qt * 64;
        const int nk = (qt >> 1) + 1;

        bf16x8 qf[4];
#pragma unroll
        for (int kc = 0; kc < 4; ++kc)
            qf[kc] = *(const bf16x8*)(Q + (size_t)(n * 2048 + q0 + wave * 16 + l16) * 128 + kc * 32 + quad * 8);

        f32x4 O[8];
#pragma unroll
        for (int h = 0; h < 8; ++h) O[h] = z4;
        float mrow[4], lrow[4];
#pragma unroll
        for (int r = 0; r < 4; ++r) { mrow[r] = -INFINITY; lrow[r] = 0.f; }

        for (int st = 0; st < nk; ++st) {
            const int s0 = st * 128;
            __syncthreads();
#pragma unroll
            for (int j = 0; j < 8; ++j) {
                gload_lds16(Kbase + (size_t)(s0 + j * 4) * 128, &sK[(wave * 32 + j * 4) * 128]);
                gload_lds16(Vbase + (size_t)j * 4 * 2048 + s0,  &sV[(wave * 32 + j * 4) * 128]);
            }
            __syncthreads();

            f32x4 S[8];
#pragma unroll
            for (int jn = 0; jn < 8; ++jn) S[jn] = z4;
#pragma unroll
            for (int jn = 0; jn < 8; ++jn) {
                int krow = jn * 16 + l16;
#pragma unroll
                for (int kc = 0; kc < 4; ++kc) {
                    bf16x8 b = *(const bf16x8*)&sK[krow * 128 + (((kc * 4 + quad) ^ l16) << 3)];
                    S[jn] = __builtin_amdgcn_mfma_f32_16x16x32_bf16(qf[kc], b, S[jn], 0, 0, 0);
                }
            }
            if (st == nk - 1) {
#pragma unroll
                for (int jn = 0; jn < 8; ++jn) {
                    int sc = s0 + jn * 16 + l16;
#pragma unroll
                    for (int r = 0; r < 4; ++r) {
                        int mr = q0 + wave * 16 + quad * 4 + r;
                        if (sc > mr) S[jn][r] = -INFINITY;
                    }
                }
            }
            float alpha[4];
#pragma unroll
            for (int r = 0; r < 4; ++r) {
                float mx = S[0][r];
#pragma unroll
                for (int jn = 1; jn < 8; ++jn) mx = fmaxf(mx, S[jn][r]);
                mx = fmaxf(mx, __shfl_xor(mx, 1));
                mx = fmaxf(mx, __shfl_xor(mx, 2));
                mx = fmaxf(mx, __shfl_xor(mx, 4));
                mx = fmaxf(mx, __shfl_xor(mx, 8));
                float mnew = fmaxf(mrow[r], mx);
                float a = __expf(mrow[r] - mnew);
                mrow[r] = mnew;
                float sum = 0.f;
#pragma unroll
                for (int jn = 0; jn < 8; ++jn) {
                    float e = __expf(S[jn][r] - mnew);
                    S[jn][r] = e;
                    sum += e;
                }
                sum += __shfl_xor(sum, 1);
                sum += __shfl_xor(sum, 2);
                sum += __shfl_xor(sum, 4);
                sum += __shfl_xor(sum, 8);
                lrow[r] = lrow[r] * a + sum;
                alpha[r] = a;
            }
#pragma unroll
            for (int h = 0; h < 8; ++h)
#pragma unroll
                for (int r = 0; r < 4; ++r) O[h][r] *= alpha[r];

            __syncthreads();
#pragma unroll
            for (int jn = 0; jn < 8; ++jn)
#pragma unroll
                for (int r = 0; r < 4; ++r) {
                    int prow = wave * 16 + quad * 4 + r;
                    int pcol = jn * 16 + l16;
                    sK[prow * 128 + ((pcol & 7) | ((((pcol >> 3) ^ prow) & 15) << 3))]
                        = f2bf(S[jn][r]);
                }
            bf16x8 pf[4];
#pragma unroll
            for (int ksv = 0; ksv < 4; ++ksv)
                pf[ksv] = *(const bf16x8*)&sK[(wave * 16 + l16) * 128 + (((ksv * 4 + quad) ^ l16) << 3)];
#pragma unroll
            for (int hj = 0; hj < 8; ++hj) {
                int vrow = hj * 16 + l16;
#pragma unroll
                for (int ksv = 0; ksv < 4; ++ksv) {
                    bf16x8 b = *(const bf16x8*)&sV[vrow * 128 + (((ksv * 4 + quad) ^ l16) << 3)];
                    O[hj] = __builtin_amdgcn_mfma_f32_16x16x32_bf16(pf[ksv], b, O[hj], 0, 0, 0);
                }
            }
        }

        // epilogue: normalize, LDS round-trip (own-wave region), swizzled 16B stores
        __syncthreads();
        uint16_t* sO = &sK[wave * 2112];
        float inv[4];
#pragma unroll
        for (int r = 0; r < 4; ++r) inv[r] = 1.0f / lrow[r];
#pragma unroll
        for (int hj = 0; hj < 8; ++hj)
#pragma unroll
            for (int r = 0; r < 4; ++r)
                sO[(quad * 4 + r) * 132 + hj * 16 + l16] = f2bf(O[hj][r] * inv[r]);
#pragma unroll
        for (int it = 0; it < 4; ++it) {
            int slot = it * 64 + lane, rloc = slot >> 4, cl = slot & 15;
            bf16x8 v = *(const bf16x8*)&sO[rloc * 132 + cl * 8];
            int R = q0 + wave * 16 + rloc;
            size_t dst = (size_t)R * 4096 + n * 128 + ((cl & 8) << 3) + (((cl & 7) ^ (R & 7)) << 3);
            *(uint4*)&att[dst] = *(uint4*)&v;
        }
    }
}

// ============================================================================
extern "C" void kernel_launch(void* const* d_in, const int* in_sizes, int n_in,
                              void* d_out, int out_size, void* d_ws, size_t ws_size,
                              hipStream_t stream) {
    const float* x   = (const float*)d_in[0];
    const int*   sp  = (const int*)d_in[1];
    const float* qw  = (const float*)d_in[3];
    const float* kvw = (const float*)d_in[4];
    const float* ow  = (const float*)d_in[5];
    const float* qsc = (const float*)d_in[6];
    const float* ksc = (const float*)d_in[7];
    float* out = (float*)d_out;

    char* ws = (char*)d_ws;
    uint16_t* xb   = (uint16_t*)(ws);
    uint16_t* Wt   = (uint16_t*)(ws + (size_t)(16u << 20));
    uint16_t* Qb   = (uint16_t*)(ws + (size_t)(64u << 20));
    uint16_t* Kb   = (uint16_t*)(ws + (size_t)(80u << 20));
    uint16_t* Vtb  = (uint16_t*)(ws + (size_t)(84u << 20));
    uint16_t* att  = (uint16_t*)(ws);                           // over dead xb
    uint16_t* Ot   = (uint16_t*)(ws + (size_t)(16u << 20));     // over dead Wt

    static bool attr_done = false;
    if (!attr_done) {
        hipFuncSetAttribute(reinterpret_cast<const void*>(k_gemm_qkv),
                            hipFuncAttributeMaxDynamicSharedMemorySize, 137216);
        hipFuncSetAttribute(reinterpret_cast<const void*>(k_gemm2p),
                            hipFuncAttributeMaxDynamicSharedMemorySize, 147456);
        attr_done = true;
    }

    k_cvt_x    <<<4096, 256, 0, stream>>>(x, xb);
    k_prep_wt  <<<dim3(2, 64, 48), 256, 0, stream>>>(qw, kvw, Wt);
    k_gemm_qkv <<<dim3(24, 8), 512, 137216, stream>>>(xb, Wt, sp, qsc, ksc, Qb, Kb, Vtb);
    k_prep_ot  <<<dim3(64, 2, 32), 256, 0, stream>>>(ow, Ot);
    k_attn     <<<dim3(16, 32), 256, 0, stream>>>(Qb, Kb, Vtb, att);
    k_gemm2p   <<<dim3(32, 8), 512, 147456, stream>>>(att, Ot, out);
}

// Round 3
// 514.402 us; speedup vs baseline: 1.1352x; 1.0316x over previous
//
#include <hip/hip_runtime.h>
#include <stdint.h>

// ============================================================================
// Attention_16441134809293 : B=1 T=2048 D=4096 N=32 KV=8 H=128, fp32 in/out.
// Round 6:
//  - k_gemm_qkv & k_gemm2p: register-level software pipeline. Phase t issues
//    ds_reads for phase t+1's fragments (double-buffered afA/afB, bfA/bfB);
//    MFMA(t) waits only a counted lgkmcnt (compiler-inserted, in-order DS),
//    so next-phase LDS reads drain under the current MFMA burst. ONE barrier
//    per phase: [reads_{t+1}] [counted vmcnt] [stage] [MFMA_t] [BAR].
//    Ledger-verified: slab confirmed >=2 phases + barrier before read-issue;
//    re-stage >=2 phases after last reads drained.
//  - k_attn unchanged.
// Workspace map (peak 88 MB):
//   phase1 (gemm1): xb[0,16M) Wt[16,64M) Q[64,80M) K[80,84M) Vt[84,88M)
//   phase2 (attn) : att[0,16M) Ot[16,48M)  (over dead xb/Wt)
// ============================================================================

typedef __bf16 bf16x8 __attribute__((ext_vector_type(8)));
typedef float  f32x4  __attribute__((ext_vector_type(4)));

__device__ __forceinline__ uint16_t f2bf(float f) {
    union { float f; uint32_t u; } v; v.f = f;
    uint32_t r = v.u + 0x7fffu + ((v.u >> 16) & 1u);   // RNE
    return (uint16_t)(r >> 16);
}

__device__ __forceinline__ void gload_lds16(const void* g, void* l) {
    __builtin_amdgcn_global_load_lds(
        (const __attribute__((address_space(1))) uint32_t*)g,
        (__attribute__((address_space(3))) uint32_t*)l, 16, 0, 0);
}

// ------------------------------------------- x -> bf16, swizzled chunk layout
__global__ __launch_bounds__(256) void k_cvt_x(const float* __restrict__ x,
                                               uint16_t* __restrict__ xb) {
    int i = (blockIdx.x * 256 + threadIdx.x) * 8;
    int r = i >> 12, k = i & 4095;
    float4 a = *(const float4*)(x + i);
    float4 b = *(const float4*)(x + i + 4);
    uint16_t tmp[8];
    tmp[0] = f2bf(a.x); tmp[1] = f2bf(a.y); tmp[2] = f2bf(a.z); tmp[3] = f2bf(a.w);
    tmp[4] = f2bf(b.x); tmp[5] = f2bf(b.y); tmp[6] = f2bf(b.z); tmp[7] = f2bf(b.w);
    int dst = r * 4096 + (k & ~63) + (((((k >> 3) & 7) ^ (r & 7))) << 3);
    *(uint4*)(xb + dst) = *(uint4*)tmp;
}

// ---------------- q_w/kv_w -> Wt[c][d] bf16 (B^T layout, c=head*128+h), swizzled
__global__ __launch_bounds__(256) void k_prep_wt(const float* __restrict__ qw,
                                                 const float* __restrict__ kvw,
                                                 uint16_t* __restrict__ Wt) {
    const int hx = blockIdx.x, dx = blockIdx.y, m = blockIdx.z;
    const float* src = (m < 32) ? (qw + (size_t)m * 524288)
                                : (kvw + (size_t)(m - 32) * 524288);
    __shared__ uint16_t tile[64][65];                            // [d][h]
    const int t = threadIdx.x, d0 = dx * 64, h0 = hx * 64;
#pragma unroll
    for (int i = 0; i < 16; ++i) {
        int idx = i * 256 + t, r = idx >> 6, c = idx & 63;
        tile[r][c] = f2bf(src[(size_t)(d0 + r) * 128 + h0 + c]);
    }
    __syncthreads();
#pragma unroll
    for (int it = 0; it < 2; ++it) {
        int slot = it * 256 + t, hr = slot >> 3, cl = slot & 7;
        int R = m * 128 + h0 + hr;
        uint16_t tmp[8];
#pragma unroll
        for (int e = 0; e < 8; ++e) tmp[e] = tile[cl * 8 + e][hr];
        *(uint4*)&Wt[(size_t)R * 4096 + d0 + ((cl ^ (R & 7)) << 3)] = *(uint4*)tmp;
    }
}

// --------------------- o_w[n][h][d] -> Ot[d][n*128+h] bf16 (B^T), swizzled
__global__ __launch_bounds__(256) void k_prep_ot(const float* __restrict__ ow,
                                                 uint16_t* __restrict__ Ot) {
    const int dx = blockIdx.x, hx = blockIdx.y, n = blockIdx.z;
    const float* src = ow + (size_t)n * 524288;                  // [128][4096]
    __shared__ uint16_t tile[64][65];                            // [h][d]
    const int t = threadIdx.x, h0 = hx * 64, d0 = dx * 64;
#pragma unroll
    for (int i = 0; i < 16; ++i) {
        int idx = i * 256 + t, r = idx >> 6, c = idx & 63;
        tile[r][c] = f2bf(src[(size_t)(h0 + r) * 4096 + d0 + c]);
    }
    __syncthreads();
#pragma unroll
    for (int it = 0; it < 2; ++it) {
        int slot = it * 256 + t, dr = slot >> 3, cl = slot & 7;
        int R = d0 + dr;
        uint16_t tmp[8];
#pragma unroll
        for (int e = 0; e < 8; ++e) tmp[e] = tile[cl * 8 + e][dr];
        *(uint4*)&Ot[(size_t)R * 4096 + n * 128 + h0 + ((cl ^ (R & 7)) << 3)] = *(uint4*)tmp;
    }
}

// ---------------------------------------------------------------- sync macros
#define PH_BAR do { asm volatile("" ::: "memory"); \
                    __builtin_amdgcn_s_barrier(); \
                    asm volatile("" ::: "memory"); } while (0)
#define WAIT_VM(N) do { asm volatile("s_waitcnt vmcnt(" #N ")" ::: "memory"); \
                        __builtin_amdgcn_sched_barrier(0); } while (0)
#define SCHED0 __builtin_amdgcn_sched_barrier(0)

// ============================================================================
// gemm1 + fused RMSNorm/RoPE epilogue, 256x256 tile, 8 waves, pipelined.
// LDS (dynamic 137216 B):
//   K-loop:  A-slabs lds[0,32768) elems  : 4 slabs of [256 rows][32 k]
//            B-slabs lds[32768,65536)    : 4 slabs of [256 rows][32 k]
//            slab = (tile&1)*2 + khalf; chunk swizzle: c ^= (row>>1)&3
//   epilogue: X fp32 [128][260] at [0,133120) ; ssq [256][4] at [133120,137216)
// Phase t: [issue ds_reads for t+1 frags] [vmcnt(4) at P0/P2] [stage 2 gloads]
//          [sched_barrier] [setprio 16xMFMA(frags_t)] [s_barrier]
// Counted compiler lgkm wait before MFMA lets reads_{t+1} drain under MFMA_t.
// ============================================================================
__global__ __launch_bounds__(512, 2) void k_gemm_qkv(const uint16_t* __restrict__ A,
                                                     const uint16_t* __restrict__ Bt,
                                                     const int* __restrict__ pos,
                                                     const float* __restrict__ qs,
                                                     const float* __restrict__ ks,
                                                     uint16_t* __restrict__ Qg,
                                                     uint16_t* __restrict__ Kg,
                                                     uint16_t* __restrict__ Vg) {
    extern __shared__ __align__(16) char smem[];
    uint16_t* lds = (uint16_t*)smem;
    const int Kd = 4096;
    const int t = threadIdx.x, wid = t >> 6, lane = t & 63;
    const int l16 = lane & 15, quad = lane >> 4;
    const int wr = wid >> 2, wc = wid & 3;
    const int bx = blockIdx.x, bm0 = blockIdx.y * 256, bn0 = bx * 256;

    f32x4 acc[8][4];
    const f32x4 z4 = {0.f, 0.f, 0.f, 0.f};
#pragma unroll
    for (int i = 0; i < 8; ++i)
#pragma unroll
        for (int j = 0; j < 4; ++j) acc[i][j] = z4;

    // ---- staging addresses (global pre-swizzled; LDS written linearly) ----
    const int r0 = wid * 16 + (lane >> 2), c4 = lane & 3;
    const int sw2 = (r0 >> 1) & 3, sw7 = r0 & 7;
    const int offK0 = (((c4 ^ sw2)) ^ sw7) * 8;        // khalf 0: logical chunk L=c^sw2
    const int offK1 = ((4 + (c4 ^ sw2)) ^ sw7) * 8;    // khalf 1: L=4+(c^sw2)
    const uint16_t* pA0 = A + (size_t)(bm0 + r0) * Kd;
    const uint16_t* pA1 = pA0 + (size_t)128 * Kd;
    const uint16_t* pB0 = Bt + (size_t)(bn0 + r0) * Kd;
    const uint16_t* pB1 = pB0 + (size_t)128 * Kd;
    uint16_t* stA = lds + wid * 512;
    uint16_t* stB = lds + 32768 + wid * 512;

    // ---- ds-read fragment bases ----
    const int sA = (l16 >> 1) & 3;
    const int rdA = (wr * 128 + l16) * 32 + ((quad ^ sA) << 3);
    const int rdB = 32768 + (wc * 64 + l16) * 32 + ((quad ^ sA) << 3);

    bf16x8 afA[4], afB[4], bfA[4], bfB[4];

#define STAGE_A(SLAB, OFF, TT) do { \
    gload_lds16(pA0 + (size_t)(TT) * 64 + (OFF), stA + (SLAB) * 8192); \
    gload_lds16(pA1 + (size_t)(TT) * 64 + (OFF), stA + (SLAB) * 8192 + 4096); } while (0)
#define STAGE_B(SLAB, OFF, TT) do { \
    gload_lds16(pB0 + (size_t)(TT) * 64 + (OFF), stB + (SLAB) * 8192); \
    gload_lds16(pB1 + (size_t)(TT) * 64 + (OFF), stB + (SLAB) * 8192 + 4096); } while (0)
#define RD_A(DST, SLAB, I0) do { _Pragma("unroll") \
    for (int i_ = 0; i_ < 4; ++i_) \
        DST[i_] = *(const bf16x8*)&lds[(SLAB) * 8192 + rdA + ((I0) + i_) * 512]; } while (0)
#define RD_B(DST, SLAB) do { _Pragma("unroll") \
    for (int j_ = 0; j_ < 4; ++j_) \
        DST[j_] = *(const bf16x8*)&lds[(SLAB) * 8192 + rdB + j_ * 512]; } while (0)
#define MFMA16(AF, BF, I0) do { __builtin_amdgcn_s_setprio(1); \
    _Pragma("unroll") for (int i_ = 0; i_ < 4; ++i_) \
        _Pragma("unroll") for (int j_ = 0; j_ < 4; ++j_) \
            acc[(I0) + i_][j_] = __builtin_amdgcn_mfma_f32_16x16x32_bf16(AF[i_], BF[j_], acc[(I0) + i_][j_], 0, 0, 0); \
    __builtin_amdgcn_s_setprio(0); } while (0)

// Phase map per tile T (BUF=T&1; A slabs a0=2B,a1=2B+1; same for B region):
//  P0: MFMA(afA=A-kh0 r0-3, bfA=B-kh0)  reads-> afB(A-kh0 r4-7)   vm4  stage A-kh1(T+1)
//  P1: MFMA(afB, bfA)                   reads-> afA(A-kh1 r0-3), bfB(B-kh1)  stage B-kh1(T+1)
//  P2: MFMA(afA, bfB)                   reads-> afB(A-kh1 r4-7)   vm4  stage A-kh0(T+2)
//  P3: MFMA(afB, bfB)                   reads-> afA(A-kh0(T+1) r0-3), bfA(B-kh0(T+1))  stage B-kh0(T+2)
#define TILE(TT, BUF) do { \
    RD_A(afB, 2*(BUF), 4); \
    WAIT_VM(4); \
    STAGE_A(2*((BUF)^1)+1, offK1, (TT)+1); \
    SCHED0; MFMA16(afA, bfA, 0); PH_BAR; \
    RD_A(afA, 2*(BUF)+1, 0); RD_B(bfB, 2*(BUF)+1); \
    STAGE_B(2*((BUF)^1)+1, offK1, (TT)+1); \
    SCHED0; MFMA16(afB, bfA, 4); PH_BAR; \
    RD_A(afB, 2*(BUF)+1, 4); \
    WAIT_VM(4); \
    STAGE_A(2*(BUF), offK0, (TT)+2); \
    SCHED0; MFMA16(afA, bfB, 0); PH_BAR; \
    RD_A(afA, 2*((BUF)^1), 0); RD_B(bfA, 2*((BUF)^1)); \
    STAGE_B(2*(BUF), offK0, (TT)+2); \
    SCHED0; MFMA16(afB, bfB, 4); PH_BAR; \
} while (0)

    // ---- prologue: stage T0 kh0/kh1 + T1 kh0 (12 loads); confirm T0-kh0 ----
    STAGE_A(0, offK0, 0); STAGE_B(0, offK0, 0);
    STAGE_A(1, offK1, 0); STAGE_B(1, offK1, 0);
    STAGE_A(2, offK0, 1); STAGE_B(2, offK0, 1);
    WAIT_VM(8);
    PH_BAR;
    RD_A(afA, 0, 0); RD_B(bfA, 0);       // frags for tile0 P0

    // ---- main loop: tiles 0..61 (stages reference tiles up to 63) ----
#pragma unroll 1
    for (int Ti = 0; Ti < 31; ++Ti) {
        TILE(2 * Ti, 0);
        TILE(2 * Ti + 1, 1);
    }

    // ---- tail: tile 62 (BUF=0, stages T63 kh1 only), tile 63 (BUF=1) ----
    RD_A(afB, 0, 4); WAIT_VM(4); STAGE_A(3, offK1, 63);
    SCHED0; MFMA16(afA, bfA, 0); PH_BAR;
    RD_A(afA, 1, 0); RD_B(bfB, 1); STAGE_B(3, offK1, 63);
    SCHED0; MFMA16(afB, bfA, 4); PH_BAR;
    RD_A(afB, 1, 4); WAIT_VM(4);
    SCHED0; MFMA16(afA, bfB, 0); PH_BAR;
    RD_A(afA, 2, 0); RD_B(bfA, 2);
    SCHED0; MFMA16(afB, bfB, 4); PH_BAR;
    RD_A(afB, 2, 4); WAIT_VM(0);
    SCHED0; MFMA16(afA, bfA, 0); PH_BAR;
    RD_A(afA, 3, 0); RD_B(bfB, 3);
    SCHED0; MFMA16(afB, bfA, 4); PH_BAR;
    RD_A(afB, 3, 4);
    SCHED0; MFMA16(afA, bfB, 0); PH_BAR;
    SCHED0; MFMA16(afB, bfB, 4);

#undef TILE
#undef MFMA16
#undef RD_B
#undef RD_A
#undef STAGE_B
#undef STAGE_A

    // ---------------- fused epilogue: RMSNorm + RoPE + store ----------------
    float* X   = (float*)smem;                 // [128][260] fp32 (row pad: no conflicts)
    float* ssq = (float*)(smem + 133120);      // [256 rows][2 heads][2 partials]

#pragma unroll
    for (int i = 0; i < 8; ++i)
#pragma unroll
        for (int r = 0; r < 4; ++r) {
            float s = 0.f;
#pragma unroll
            for (int j = 0; j < 4; ++j) s += acc[i][j][r] * acc[i][j][r];
            s += __shfl_xor(s, 1); s += __shfl_xor(s, 2);
            s += __shfl_xor(s, 4); s += __shfl_xor(s, 8);
            if (l16 == 0)
                ssq[(wr * 128 + i * 16 + quad * 4 + r) * 4 + (wc >> 1) * 2 + (wc & 1)] = s;
        }
    __syncthreads();

    const int cat = (bx < 16) ? 0 : (bx < 20 ? 1 : 2);   // 0=Q 1=K 2=V (head pairs never straddle)
    float s1 = 0.f, s2 = 0.f, invts = 0.f;
    if (cat < 2) {
        const float* sc = cat ? ks : qs;
        s1 = 1.0f + sc[lane];
        s2 = 1.0f + sc[lane + 64];
        invts = exp2f((float)lane * -0.20762050593046014f);  // 10000^(-h/64)
    }

#pragma unroll
    for (int pass = 0; pass < 2; ++pass) {
        if (wr == pass) {
#pragma unroll
            for (int i = 0; i < 8; ++i)
#pragma unroll
                for (int j = 0; j < 4; ++j)
#pragma unroll
                    for (int r = 0; r < 4; ++r)
                        X[(i * 16 + quad * 4 + r) * 260 + wc * 64 + j * 16 + l16] = acc[i][j][r];
        }
        __syncthreads();
        // RMSNorm + RoPE in place; wave handles 16 rows, lane = h in [0,64)
        for (int rr = 0; rr < 16; ++rr) {
            const int lrow = wid * 16 + rr;
            const int grow = bm0 + pass * 128 + lrow;
            float sn = 0.f, cs = 0.f;
            if (cat < 2) {
                float ang = (float)pos[grow] * invts;
                __sincosf(ang, &sn, &cs);
            }
#pragma unroll
            for (int hh = 0; hh < 2; ++hh) {
                const int sb = (pass * 128 + lrow) * 4 + hh * 2;
                float rn = rsqrtf((ssq[sb] + ssq[sb + 1]) * 0.0078125f + 1e-6f);
                float x1 = X[lrow * 260 + hh * 128 + lane];
                float x2 = X[lrow * 260 + hh * 128 + 64 + lane];
                if (cat < 2) {
                    float y1 = x1 * rn * s1, y2 = x2 * rn * s2;
                    X[lrow * 260 + hh * 128 + lane]      = y1 * cs - y2 * sn;
                    X[lrow * 260 + hh * 128 + 64 + lane] = y2 * cs + y1 * sn;
                } else {
                    X[lrow * 260 + hh * 128 + lane]      = x1 * rn;
                    X[lrow * 260 + hh * 128 + 64 + lane] = x2 * rn;
                }
            }
        }
        __syncthreads();
        // stores (bf16): 2 heads x 128 rows x 16 chunks = 4096 chunks, 8 iters
        if (cat == 2) {
            // V: transposed to Vt[(kv*128+h)][s], chunks swizzled by h&15 per 128-s block
#pragma unroll
            for (int it = 0; it < 8; ++it) {
                int slot = it * 512 + t, hh = slot >> 11, rem = slot & 2047;
                int h = rem >> 4, sc2 = rem & 15;
                uint16_t tmp[8];
#pragma unroll
                for (int e = 0; e < 8; ++e)
                    tmp[e] = f2bf(X[(sc2 * 8 + e) * 260 + hh * 128 + h]);
                int n = bx * 2 + hh;
                *(uint4*)&Vg[((size_t)(n - 40) * 128 + h) * 2048 + (bm0 + pass * 128)
                             + ((sc2 ^ (h & 15)) << 3)] = *(uint4*)tmp;
            }
        } else {
#pragma unroll
            for (int it = 0; it < 8; ++it) {
                int slot = it * 512 + t, hh = slot >> 11, rem = slot & 2047;
                int lrow = rem >> 4, c = rem & 15;
                int tg = bm0 + pass * 128 + lrow, n = bx * 2 + hh;
                f32x4 a = *(f32x4*)&X[lrow * 260 + hh * 128 + c * 8];
                f32x4 b = *(f32x4*)&X[lrow * 260 + hh * 128 + c * 8 + 4];
                uint16_t tmp[8];
#pragma unroll
                for (int e = 0; e < 4; ++e) { tmp[e] = f2bf(a[e]); tmp[4 + e] = f2bf(b[e]); }
                if (cat == 0)
                    *(uint4*)&Qg[((size_t)n * 2048 + tg) * 128 + c * 8] = *(uint4*)tmp;
                else  // K: pre-swizzled chunks by tg&15 for attn's global_load_lds
                    *(uint4*)&Kg[((size_t)(n - 32) * 2048 + tg) * 128
                                 + ((c ^ (tg & 15)) << 3)] = *(uint4*)tmp;
            }
        }
        __syncthreads();
    }
}

// ============================================================================
// gemm2: out = att(2048x4096) * Ot^T(4096x4096), pipelined 256x128 tile.
// 256 blocks (full CU coverage), 8 waves (4x2), per-wave 64x64, acc[4][4].
// LDS 147456 B: A 6 slabs x [256][32k] + B 6 slabs x [128][32k] = 3-tile ring.
// Phase i (slab s=i%6): [reads s+1 frags (alt set)] [vmcnt(3)] [stage slab
// (i+4)%6] [MFMA frags_i] [BAR]. Counted lgkm wait (compiler) overlaps reads
// with MFMA; vmcnt(3) retires the group staged 2 phases prior (L2-resident).
// ============================================================================
__global__ __launch_bounds__(512, 2) void k_gemm2p(const uint16_t* __restrict__ A,
                                                   const uint16_t* __restrict__ Bt,
                                                   float* __restrict__ C) {
    extern __shared__ __align__(16) char smem2[];
    uint16_t* lds = (uint16_t*)smem2;
    const int Kd = 4096, Nn = 4096;
    const int t = threadIdx.x, wid = t >> 6, lane = t & 63;
    const int l16 = lane & 15, quad = lane >> 4;
    const int wr = wid >> 1, wc = wid & 1;
    const int bm0 = blockIdx.y * 256, bn0 = blockIdx.x * 128;

    f32x4 acc[4][4];
    const f32x4 z4 = {0.f, 0.f, 0.f, 0.f};
#pragma unroll
    for (int i = 0; i < 4; ++i)
#pragma unroll
        for (int j = 0; j < 4; ++j) acc[i][j] = z4;

    const int r0 = wid * 16 + (lane >> 2), c4 = lane & 3;
    const int sw2 = (r0 >> 1) & 3, sw7 = r0 & 7;
    const int offK0 = ((c4 ^ sw2) ^ sw7) * 8;
    const int offK1 = ((4 + (c4 ^ sw2)) ^ sw7) * 8;
    const uint16_t* pA0 = A + (size_t)(bm0 + r0) * Kd;
    const uint16_t* pA1 = pA0 + (size_t)128 * Kd;
    const uint16_t* pB0 = Bt + (size_t)(bn0 + r0) * Kd;
    uint16_t* stA = lds + wid * 512;
    uint16_t* stB = lds + 49152 + wid * 512;

    const int sA = (l16 >> 1) & 3;
    const int rdA = (wr * 64 + l16) * 32 + ((quad ^ sA) << 3);
    const int rdB = 49152 + (wc * 64 + l16) * 32 + ((quad ^ sA) << 3);

    bf16x8 afA[4], afB[4], bfA[4], bfB[4];

#define G2_STAGE(SLAB, OFF, TT) do { \
    gload_lds16(pA0 + (size_t)(TT) * 64 + (OFF), stA + (SLAB) * 8192); \
    gload_lds16(pA1 + (size_t)(TT) * 64 + (OFF), stA + (SLAB) * 8192 + 4096); \
    gload_lds16(pB0 + (size_t)(TT) * 64 + (OFF), stB + (SLAB) * 4096); } while (0)
#define G2_RD(AD, BD, CS) do { _Pragma("unroll") \
    for (int i_ = 0; i_ < 4; ++i_) \
        AD[i_] = *(const bf16x8*)&lds[(CS) * 8192 + rdA + i_ * 512]; \
    _Pragma("unroll") for (int j_ = 0; j_ < 4; ++j_) \
        BD[j_] = *(const bf16x8*)&lds[(CS) * 4096 + rdB + j_ * 512]; } while (0)
#define G2_MFMA(AF, BF) do { __builtin_amdgcn_s_setprio(1); \
    _Pragma("unroll") for (int i_ = 0; i_ < 4; ++i_) \
        _Pragma("unroll") for (int j_ = 0; j_ < 4; ++j_) \
            acc[i_][j_] = __builtin_amdgcn_mfma_f32_16x16x32_bf16(AF[i_], BF[j_], acc[i_][j_], 0, 0, 0); \
    __builtin_amdgcn_s_setprio(0); } while (0)

#define G2_PH(RA, RB, CSN, SST, OFF, TT, MA, MB) do { \
    G2_RD(RA, RB, CSN); \
    WAIT_VM(3); \
    G2_STAGE(SST, OFF, TT); \
    SCHED0; G2_MFMA(MA, MB); PH_BAR; } while (0)

    // prologue: stage slabs for phases 0..3 (12 loads); confirm phases 0,1
    G2_STAGE(0, offK0, 0);
    G2_STAGE(1, offK1, 0);
    G2_STAGE(2, offK0, 1);
    G2_STAGE(3, offK1, 1);
    WAIT_VM(6);
    PH_BAR;
    G2_RD(afA, bfA, 0);                  // frags for phase 0

    // main loop: phases 0..119 (tiles 0..59); stage at phase i -> slab (i+4)%6
#pragma unroll 1
    for (int m = 0; m < 20; ++m) {
        G2_PH(afB, bfB, 1, 4, offK0, 3*m + 2, afA, bfA);
        G2_PH(afA, bfA, 2, 5, offK1, 3*m + 2, afB, bfB);
        G2_PH(afB, bfB, 3, 0, offK0, 3*m + 3, afA, bfA);
        G2_PH(afA, bfA, 4, 1, offK1, 3*m + 3, afB, bfB);
        G2_PH(afB, bfB, 5, 2, offK0, 3*m + 4, afA, bfA);
        G2_PH(afA, bfA, 0, 3, offK1, 3*m + 4, afB, bfB);
    }
    // phases 120..123 (tiles 60,61): stage tiles 62,63
    G2_PH(afB, bfB, 1, 4, offK0, 62, afA, bfA);
    G2_PH(afA, bfA, 2, 5, offK1, 62, afB, bfB);
    G2_PH(afB, bfB, 3, 0, offK0, 63, afA, bfA);
    G2_PH(afA, bfA, 4, 1, offK1, 63, afB, bfB);
    // phases 124..127 (tiles 62,63): drain
    G2_RD(afB, bfB, 5); WAIT_VM(3); SCHED0; G2_MFMA(afA, bfA); PH_BAR;
    G2_RD(afA, bfA, 0); WAIT_VM(0); SCHED0; G2_MFMA(afB, bfB); PH_BAR;
    G2_RD(afB, bfB, 1);              SCHED0; G2_MFMA(afA, bfA); PH_BAR;
    SCHED0; G2_MFMA(afB, bfB);

#undef G2_PH
#undef G2_MFMA
#undef G2_RD
#undef G2_STAGE

#pragma unroll
    for (int i = 0; i < 4; ++i)
#pragma unroll
        for (int j = 0; j < 4; ++j) {
            int row = bm0 + wr * 64 + i * 16 + quad * 4;
            int col = bn0 + wc * 64 + j * 16 + l16;
            float* cp = C + (size_t)row * Nn + col;
            cp[0]              = acc[i][j][0];
            cp[(size_t)Nn]     = acc[i][j][1];
            cp[2 * (size_t)Nn] = acc[i][j][2];
            cp[3 * (size_t)Nn] = acc[i][j][3];
        }
}

// ----------------- Flash attention, causal, GQA. Balanced (p, 31-p) pairing.
// K/Vt staged via global_load_lds (identity copy of pre-swizzled global).
__global__ __launch_bounds__(256) void k_attn(const uint16_t* __restrict__ Q,
                                              const uint16_t* __restrict__ K,
                                              const uint16_t* __restrict__ Vt,
                                              uint16_t* __restrict__ att) {
    __shared__ uint16_t sK[128 * 128];
    __shared__ uint16_t sV[128 * 128];
    const int p = blockIdx.x, n = blockIdx.y, kk = n >> 2;
    const int t = threadIdx.x, wave = t >> 6, lane = t & 63;
    const int l16 = lane & 15, quad = lane >> 4;
    const f32x4 z4 = {0.f, 0.f, 0.f, 0.f};

    const uint16_t* Kbase = K  + ((size_t)kk * 2048 + wave * 32 + (lane >> 4)) * 128 + (lane & 15) * 8;
    const uint16_t* Vbase = Vt + ((size_t)kk * 128  + wave * 32 + (lane >> 4)) * 2048 + (lane & 15) * 8;

    for (int half = 0; half < 2; ++half) {
        const int qt = half ? (31 - p) : p;
        const int q0 = qt * 64;
        const int nk = (qt >> 1) + 1;

        bf16x8 qf[4];
#pragma unroll
        for (int kc = 0; kc < 4; ++kc)
            qf[kc] = *(const bf16x8*)(Q + (size_t)(n * 2048 + q0 + wave * 16 + l16) * 128 + kc * 32 + quad * 8);

        f32x4 O[8];
#pragma unroll
        for (int h = 0; h < 8; ++h) O[h] = z4;
        float mrow[4], lrow[4];
#pragma unroll
        for (int r = 0; r < 4; ++r) { mrow[r] = -INFINITY; lrow[r] = 0.f; }

        for (int st = 0; st < nk; ++st) {
            const int s0 = st * 128;
            __syncthreads();
#pragma unroll
            for (int j = 0; j < 8; ++j) {
                gload_lds16(Kbase + (size_t)(s0 + j * 4) * 128, &sK[(wave * 32 + j * 4) * 128]);
                gload_lds16(Vbase + (size_t)j * 4 * 2048 + s0,  &sV[(wave * 32 + j * 4) * 128]);
            }
            __syncthreads();

            f32x4 S[8];
#pragma unroll
            for (int jn = 0; jn < 8; ++jn) S[jn] = z4;
#pragma unroll
            for (int jn = 0; jn < 8; ++jn) {
                int krow = jn * 16 + l16;
#pragma unroll
                for (int kc = 0; kc < 4; ++kc) {
                    bf16x8 b = *(const bf16x8*)&sK[krow * 128 + (((kc * 4 + quad) ^ l16) << 3)];
                    S[jn] = __builtin_amdgcn_mfma_f32_16x16x32_bf16(qf[kc], b, S[jn], 0, 0, 0);
                }
            }
            if (st == nk - 1) {
#pragma unroll
                for (int jn = 0; jn < 8; ++jn) {
                    int sc = s0 + jn * 16 + l16;
#pragma unroll
                    for (int r = 0; r < 4; ++r) {
                        int mr = q0 + wave * 16 + quad * 4 + r;
                        if (sc > mr) S[jn][r] = -INFINITY;
                    }
                }
            }
            float alpha[4];
#pragma unroll
            for (int r = 0; r < 4; ++r) {
                float mx = S[0][r];
#pragma unroll
                for (int jn = 1; jn < 8; ++jn) mx = fmaxf(mx, S[jn][r]);
                mx = fmaxf(mx, __shfl_xor(mx, 1));
                mx = fmaxf(mx, __shfl_xor(mx, 2));
                mx = fmaxf(mx, __shfl_xor(mx, 4));
                mx = fmaxf(mx, __shfl_xor(mx, 8));
                float mnew = fmaxf(mrow[r], mx);
                float a = __expf(mrow[r] - mnew);
                mrow[r] = mnew;
                float sum = 0.f;
#pragma unroll
                for (int jn = 0; jn < 8; ++jn) {
                    float e = __expf(S[jn][r] - mnew);
                    S[jn][r] = e;
                    sum += e;
                }
                sum += __shfl_xor(sum, 1);
                sum += __shfl_xor(sum, 2);
                sum += __shfl_xor(sum, 4);
                sum += __shfl_xor(sum, 8);
                lrow[r] = lrow[r] * a + sum;
                alpha[r] = a;
            }
#pragma unroll
            for (int h = 0; h < 8; ++h)
#pragma unroll
                for (int r = 0; r < 4; ++r) O[h][r] *= alpha[r];

            __syncthreads();
#pragma unroll
            for (int jn = 0; jn < 8; ++jn)
#pragma unroll
                for (int r = 0; r < 4; ++r) {
                    int prow = wave * 16 + quad * 4 + r;
                    int pcol = jn * 16 + l16;
                    sK[prow * 128 + ((pcol & 7) | ((((pcol >> 3) ^ prow) & 15) << 3))]
                        = f2bf(S[jn][r]);
                }
            bf16x8 pf[4];
#pragma unroll
            for (int ksv = 0; ksv < 4; ++ksv)
                pf[ksv] = *(const bf16x8*)&sK[(wave * 16 + l16) * 128 + (((ksv * 4 + quad) ^ l16) << 3)];
#pragma unroll
            for (int hj = 0; hj < 8; ++hj) {
                int vrow = hj * 16 + l16;
#pragma unroll
                for (int ksv = 0; ksv < 4; ++ksv) {
                    bf16x8 b = *(const bf16x8*)&sV[vrow * 128 + (((ksv * 4 + quad) ^ l16) << 3)];
                    O[hj] = __builtin_amdgcn_mfma_f32_16x16x32_bf16(pf[ksv], b, O[hj], 0, 0, 0);
                }
            }
        }

        // epilogue: normalize, LDS round-trip (own-wave region), swizzled 16B stores
        __syncthreads();
        uint16_t* sO = &sK[wave * 2112];
        float inv[4];
#pragma unroll
        for (int r = 0; r < 4; ++r) inv[r] = 1.0f / lrow[r];
#pragma unroll
        for (int hj = 0; hj < 8; ++hj)
#pragma unroll
            for (int r = 0; r < 4; ++r)
                sO[(quad * 4 + r) * 132 + hj * 16 + l16] = f2bf(O[hj][r] * inv[r]);
#pragma unroll
        for (int it = 0; it < 4; ++it) {
            int slot = it * 64 + lane, rloc = slot >> 4, cl = slot & 15;
            bf16x8 v = *(const bf16x8*)&sO[rloc * 132 + cl * 8];
            int R = q0 + wave * 16 + rloc;
            size_t dst = (size_t)R * 4096 + n * 128 + ((cl & 8) << 3) + (((cl & 7) ^ (R & 7)) << 3);
            *(uint4*)&att[dst] = *(uint4*)&v;
        }
    }
}

// ============================================================================
extern "C" void kernel_launch(void* const* d_in, const int* in_sizes, int n_in,
                              void* d_out, int out_size, void* d_ws, size_t ws_size,
                              hipStream_t stream) {
    const float* x   = (const float*)d_in[0];
    const int*   sp  = (const int*)d_in[1];
    const float* qw  = (const float*)d_in[3];
    const float* kvw = (const float*)d_in[4];
    const float* ow  = (const float*)d_in[5];
    const float* qsc = (const float*)d_in[6];
    const float* ksc = (const float*)d_in[7];
    float* out = (float*)d_out;

    char* ws = (char*)d_ws;
    uint16_t* xb   = (uint16_t*)(ws);
    uint16_t* Wt   = (uint16_t*)(ws + (size_t)(16u << 20));
    uint16_t* Qb   = (uint16_t*)(ws + (size_t)(64u << 20));
    uint16_t* Kb   = (uint16_t*)(ws + (size_t)(80u << 20));
    uint16_t* Vtb  = (uint16_t*)(ws + (size_t)(84u << 20));
    uint16_t* att  = (uint16_t*)(ws);                           // over dead xb
    uint16_t* Ot   = (uint16_t*)(ws + (size_t)(16u << 20));     // over dead Wt

    static bool attr_done = false;
    if (!attr_done) {
        hipFuncSetAttribute(reinterpret_cast<const void*>(k_gemm_qkv),
                            hipFuncAttributeMaxDynamicSharedMemorySize, 137216);
        hipFuncSetAttribute(reinterpret_cast<const void*>(k_gemm2p),
                            hipFuncAttributeMaxDynamicSharedMemorySize, 147456);
        attr_done = true;
    }

    k_cvt_x    <<<4096, 256, 0, stream>>>(x, xb);
    k_prep_wt  <<<dim3(2, 64, 48), 256, 0, stream>>>(qw, kvw, Wt);
    k_gemm_qkv <<<dim3(24, 8), 512, 137216, stream>>>(xb, Wt, sp, qsc, ksc, Qb, Kb, Vtb);
    k_prep_ot  <<<dim3(64, 2, 32), 256, 0, stream>>>(ow, Ot);
    k_attn     <<<dim3(16, 32), 256, 0, stream>>>(Qb, Kb, Vtb, att);
    k_gemm2p   <<<dim3(32, 8), 512, 147456, stream>>>(att, Ot, out);
}